// Round 2
// 958.131 us; speedup vs baseline: 1.2258x; 1.2258x over previous
//
#include <hip/hip_runtime.h>
#include <cstdint>
#include <cstddef>

#define D_DIM 256
#define E_DIM 512
#define S_DIM 128
#define B_DIM 1024
#define T_SEQ 133
#define T_PAD 144
#define N_UV 1152
#define NTOK (B_DIM * T_SEQ)      // 136192 = 1064*128
#define CB 256                    // batches per chunk
#define NCHUNK (B_DIM / CB)       // 4
#define CH_ROWS (CB * T_SEQ)      // 34048 = 266*128
#define EPSF 1e-5f
#define RSQRT_S 0.08838834764831845f

typedef __attribute__((ext_vector_type(8))) short short8;
typedef __attribute__((ext_vector_type(4))) float floatx4;
#define MFMA16(a, b, c) __builtin_amdgcn_mfma_f32_16x16x32_bf16((a), (b), (c), 0, 0, 0)

__device__ __forceinline__ unsigned short f2bf(float f) {
    union { float f; unsigned u; } a; a.f = f;
    unsigned r = a.u + 0x7fffu + ((a.u >> 16) & 1u);
    return (unsigned short)(r >> 16);
}
__device__ __forceinline__ float bf2f(unsigned short h) {
    union { unsigned u; float f; } a; a.u = ((unsigned)h) << 16;
    return a.f;
}

// async global->LDS, 16B per lane; LDS dest = wave-uniform base + lane*16.
// Both pointer args built via integer casts (no address-space pointer casts):
// global generic VA == as1 VA bit-for-bit; LDS generic VA low 32 bits == LDS
// byte offset on gfx9+ (shared aperture low bits are zero).
__device__ __forceinline__ void gload16(const unsigned short* g, const unsigned short* l) {
    __builtin_amdgcn_global_load_lds(
        (const __attribute__((address_space(1))) unsigned int*)(uintptr_t)g,
        (__attribute__((address_space(3))) unsigned int*)(unsigned)(uintptr_t)l,
        16, 0, 0);
}

// ---------------------------------------------------------------------------
// Cast weights to bf16 once per launch.
// ---------------------------------------------------------------------------
__global__ __launch_bounds__(256) void k_castw(const float* __restrict__ Wuv,
                                               const float* __restrict__ Wo,
                                               unsigned short* __restrict__ Wuvb,
                                               unsigned short* __restrict__ Wob) {
    int i4 = blockIdx.x * 256 + threadIdx.x;
    const int nuv4 = (N_UV * D_DIM) / 4;
    float4 f;
    unsigned short* dst;
    if (i4 < nuv4) { f = ((const float4*)Wuv)[i4]; dst = Wuvb + (size_t)i4 * 4; }
    else { int j = i4 - nuv4; f = ((const float4*)Wo)[j]; dst = Wob + (size_t)j * 4; }
    dst[0] = f2bf(f.x); dst[1] = f2bf(f.y); dst[2] = f2bf(f.z); dst[3] = f2bf(f.w);
}

// ---------------------------------------------------------------------------
// K0: rms-normalize ALL tokens -> bf16 xn. One wave per token. Full batch.
// ---------------------------------------------------------------------------
__global__ __launch_bounds__(256) void k_rms(const float* __restrict__ x,
                                             const float* __restrict__ g,
                                             unsigned short* __restrict__ xn) {
    int wid  = blockIdx.x * 4 + (threadIdx.x >> 6);
    int lane = threadIdx.x & 63;
    float4 vv = ((const float4*)(x + (size_t)wid * D_DIM))[lane];
    float s = vv.x*vv.x + vv.y*vv.y + vv.z*vv.z + vv.w*vv.w;
#pragma unroll
    for (int off = 1; off < 64; off <<= 1) s += __shfl_xor(s, off, 64);
    float sc = g[0] / fmaxf(sqrtf(s) * 0.0625f, EPSF);
    unsigned short o[4] = {f2bf(vv.x*sc), f2bf(vv.y*sc), f2bf(vv.z*sc), f2bf(vv.w*sc)};
    *(ushort4*)(xn + (size_t)wid * D_DIM + lane * 4) = *(const ushort4*)o;
}

// ---------------------------------------------------------------------------
// K1: uv = silu(xn @ Wuv^T). m97 structure: 128x128 tile, BK=32,
// global_load_lds width-16, source-permuted LDS swizzle (2-way banked reads).
// Grid (CH_ROWS/128=266, 9). Col-blocks 0..3 -> u, 4..7 -> vT, 8 -> q/k.
// ---------------------------------------------------------------------------
__global__ __launch_bounds__(256) void k_gemm1(
    const unsigned short* __restrict__ xn,    // [CH_ROWS][256] chunk-local
    const unsigned short* __restrict__ Wuvb,  // [1152][256]
    const float* __restrict__ gamma, const float* __restrict__ beta,
    unsigned short* __restrict__ u,           // [CH_ROWS][512] chunk-local
    unsigned short* __restrict__ vTg,         // [CB][512][T_PAD]
    unsigned short* __restrict__ q,           // [CH_ROWS][128]
    unsigned short* __restrict__ kk) {        // [CH_ROWS][128]
    __shared__ __align__(16) unsigned short As[128 * 32];
    __shared__ __align__(16) unsigned short Bs[128 * 32];
    const int tid = threadIdx.x;
    const int w = tid >> 6, lane = tid & 63, m = lane & 15, quad = lane >> 4;
    const int wr = w >> 1, wc = w & 1;
    const int row0 = blockIdx.x * 128, col0 = blockIdx.y * 128;

    // staging: wave w lane l covers LDS row w*16+(l>>2) (lA0) / +64 (lA1),
    // 16B slot (l&3). Source col slot permuted: LDS(row,s)=glob(row, s^((row>>1)&3)).
    const int srow = lane >> 2;
    const int scol = ((lane & 3) ^ ((lane >> 3) & 3)) * 8;
    const unsigned short* gA0 = xn   + (size_t)(row0 + w*16      + srow) * D_DIM + scol;
    const unsigned short* gA1 = xn   + (size_t)(row0 + w*16 + 64 + srow) * D_DIM + scol;
    const unsigned short* gB0 = Wuvb + (size_t)(col0 + w*16      + srow) * D_DIM + scol;
    const unsigned short* gB1 = Wuvb + (size_t)(col0 + w*16 + 64 + srow) * D_DIM + scol;
    const unsigned short* lA0 = As + w * 512;
    const unsigned short* lA1 = As + (w + 4) * 512;
    const unsigned short* lB0 = Bs + w * 512;
    const unsigned short* lB1 = Bs + (w + 4) * 512;

    floatx4 acc[4][4];
#pragma unroll
    for (int i = 0; i < 4; ++i)
#pragma unroll
        for (int j = 0; j < 4; ++j) acc[i][j] = (floatx4){0.f,0.f,0.f,0.f};

    const int aswz = (quad ^ ((m >> 1) & 3)) * 8;   // read-side inverse swizzle

    for (int k0 = 0; k0 < D_DIM; k0 += 32) {
        gload16(gA0 + k0, lA0);
        gload16(gA1 + k0, lA1);
        gload16(gB0 + k0, lB0);
        gload16(gB1 + k0, lB1);
        __syncthreads();                      // vmcnt(0) drain (compiler-emitted)
        short8 a[4], b[4];
#pragma unroll
        for (int t = 0; t < 4; ++t) {
            a[t] = *(const short8*)&As[(wr*64 + t*16 + m) * 32 + aswz];
            b[t] = *(const short8*)&Bs[(wc*64 + t*16 + m) * 32 + aswz];
        }
#pragma unroll
        for (int i = 0; i < 4; ++i)
#pragma unroll
            for (int j = 0; j < 4; ++j) acc[i][j] = MFMA16(a[i], b[j], acc[i][j]);
        __syncthreads();
    }

    const int rbase = row0 + wr*64 + quad*4;
    const int cbase = col0 + wc*64 + m;
#pragma unroll
    for (int it = 0; it < 4; ++it)
#pragma unroll
        for (int jt = 0; jt < 4; ++jt)
#pragma unroll
            for (int r = 0; r < 4; ++r) {
                const int row = rbase + it*16 + r;
                const int col = cbase + jt*16;
                float val = acc[it][jt][r];
                val = val / (1.0f + __expf(-val));   // silu
                if (col0 < E_DIM) {
                    u[(size_t)row * E_DIM + col] = f2bf(val);
                } else if (col0 < 2*E_DIM) {
                    const int e = col - E_DIM;
                    const unsigned bb = (unsigned)row / 133u;
                    const unsigned tt = (unsigned)row - bb * 133u;
                    vTg[(size_t)bb * (E_DIM*T_PAD) + (size_t)e * T_PAD + tt] = f2bf(val);
                } else {
                    const int s = col - 2*E_DIM;
                    q[(size_t)row * S_DIM + s]  = f2bf(fmaf(val, gamma[s],        beta[s]));
                    kk[(size_t)row * S_DIM + s] = f2bf(fmaf(val, gamma[S_DIM+s], beta[S_DIM+s]));
                }
            }
}

// ---------------------------------------------------------------------------
// K2: attention. Grid (12, CB): x = ec(0..3) + 4*ig(0..2), y = local batch.
// Verified baseline structure; + s_setprio around MFMA, guarded V-tail load.
// ---------------------------------------------------------------------------
__global__ __launch_bounds__(256) void k_attn(
    const unsigned short* __restrict__ q,
    const unsigned short* __restrict__ kk,
    const unsigned short* __restrict__ vTg,
    unsigned short* __restrict__ u) {
    __shared__ __align__(16) unsigned short ksh[64][136];  // 17408 B (reused for O)
    __shared__ __align__(16) unsigned short kern[48][72];  //  6912 B
    __shared__ __align__(16) unsigned short vTs[128][72];  // 18432 B
    const int tid = threadIdx.x;
    const int ec = blockIdx.x & 3;
    const int ig = blockIdx.x >> 2;
    const int b  = blockIdx.y;
    const int w = tid >> 6, lane = tid & 63, m = lane & 15, quad = lane >> 4;
    const size_t qs0 = (size_t)b * T_SEQ * S_DIM;
    const size_t us0 = (size_t)b * T_SEQ * E_DIM;
    const unsigned short* vTb = vTg + (size_t)b * E_DIM * T_PAD + (size_t)ec * 128 * T_PAD;

    short8 qf[3][4];
#pragma unroll
    for (int it = 0; it < 3; ++it) {
        int ri = ig * 48 + it * 16 + m;
        if (ri > T_SEQ - 1) ri = T_SEQ - 1;
        const unsigned short* qp = q + qs0 + (size_t)ri * S_DIM + quad * 8;
#pragma unroll
        for (int ks = 0; ks < 4; ++ks) qf[it][ks] = *(const short8*)(qp + ks * 32);
    }

    floatx4 oa[3][2];
#pragma unroll
    for (int it = 0; it < 3; ++it) {
        oa[it][0] = (floatx4){0.f,0.f,0.f,0.f};
        oa[it][1] = (floatx4){0.f,0.f,0.f,0.f};
    }
    const short8 z8 = {0,0,0,0,0,0,0,0};

    for (int j0 = 0; j0 < T_SEQ; j0 += 64) {
        // stage k-tile [64][128], zero rows >= T
        for (int idx = tid; idx < 1024; idx += 256) {
            int r = idx >> 4, c8 = (idx & 15) * 8;
            short8 val = z8;
            if (j0 + r < T_SEQ)
                val = *(const short8*)(kk + qs0 + (size_t)(j0 + r) * S_DIM + c8);
            *(short8*)&ksh[r][c8] = val;
        }
        // stage v-tile vTs[e][j], zero cols >= T (pad cols may hold poison)
        for (int idx = tid; idx < 1024; idx += 256) {
            int e = idx >> 3, j8 = idx & 7;
            int jb = j0 + j8 * 8;
            short8 val = z8;
            if (jb + 8 <= T_SEQ) {
                val = *(const short8*)(vTb + (size_t)e * T_PAD + jb);
            } else if (jb < T_SEQ) {
#pragma unroll
                for (int t = 0; t < 8; ++t)
                    if (jb + t < T_SEQ) val[t] = (short)vTb[(size_t)e * T_PAD + jb + t];
            }
            *(short8*)&vTs[e][j8 * 8] = val;
        }
        __syncthreads();

        // phase 1: wave w computes kern cols [w*16, w*16+16) for all 3 i-tiles
        short8 kbf[4];
#pragma unroll
        for (int ks = 0; ks < 4; ++ks)
            kbf[ks] = *(const short8*)&ksh[w*16 + m][ks*32 + quad*8];
        __builtin_amdgcn_s_setprio(1);
#pragma unroll
        for (int it = 0; it < 3; ++it) {
            floatx4 c = (floatx4){0.f,0.f,0.f,0.f};
#pragma unroll
            for (int ks = 0; ks < 4; ++ks) c = MFMA16(qf[it][ks], kbf[ks], c);
#pragma unroll
            for (int r = 0; r < 4; ++r) {
                float sv = fmaxf(c[r] * RSQRT_S, 0.0f);
                kern[it*16 + quad*4 + r][w*16 + m] = f2bf(sv * sv);
            }
        }
        __builtin_amdgcn_s_setprio(0);
        __syncthreads();

        // phase 2: wave w owns e-frags {2w, 2w+1}; O += kern @ v
        __builtin_amdgcn_s_setprio(1);
#pragma unroll
        for (int ef = 0; ef < 2; ++ef) {
            const int eb = w * 2 + ef;
            short8 b0 = *(const short8*)&vTs[eb*16 + m][quad*8];
            short8 b1 = *(const short8*)&vTs[eb*16 + m][32 + quad*8];
#pragma unroll
            for (int it = 0; it < 3; ++it) {
                short8 a0 = *(const short8*)&kern[it*16 + m][quad*8];
                short8 a1 = *(const short8*)&kern[it*16 + m][32 + quad*8];
                oa[it][ef] = MFMA16(a0, b0, oa[it][ef]);
                oa[it][ef] = MFMA16(a1, b1, oa[it][ef]);
            }
        }
        __builtin_amdgcn_s_setprio(0);
        __syncthreads();
    }

    // stage O into LDS (reuse ksh as [48][136])
#pragma unroll
    for (int it = 0; it < 3; ++it)
#pragma unroll
        for (int ef = 0; ef < 2; ++ef) {
            const int eb = w * 2 + ef;
#pragma unroll
            for (int r = 0; r < 4; ++r)
                ksh[it*16 + quad*4 + r][eb*16 + m] = f2bf(oa[it][ef][r]);
        }
    __syncthreads();

    // h = u * O, coalesced 16B rows
    for (int idx = tid; idx < 48 * 16; idx += 256) {
        const int rl = idx >> 4, c8 = (idx & 15) * 8;
        const int grow = ig * 48 + rl;
        if (grow < T_SEQ) {
            const size_t ad = us0 + (size_t)grow * E_DIM + ec * 128 + c8;
            short8 uv = *(const short8*)(u + ad);
            unsigned short hv[8];
#pragma unroll
            for (int i = 0; i < 8; ++i)
                hv[i] = f2bf(bf2f((unsigned short)uv[i]) * bf2f(ksh[rl][c8 + i]));
            *(short8*)(u + ad) = *(const short8*)hv;
        }
    }
}

// ---------------------------------------------------------------------------
// K3: out = h @ Wo^T + x*res_scale. Full batch, m97 structure 128x128 tile.
// Grid (NTOK/128 = 1064, 2). K = 512.
// ---------------------------------------------------------------------------
__global__ __launch_bounds__(256) void k_gemm2(
    const unsigned short* __restrict__ h,     // [NTOK][512]
    const unsigned short* __restrict__ Wob,   // [256][512]
    const float* __restrict__ x, const float* __restrict__ resS,
    float* __restrict__ out) {
    __shared__ __align__(16) unsigned short As[128 * 32];
    __shared__ __align__(16) unsigned short Bs[128 * 32];
    const int tid = threadIdx.x;
    const int w = tid >> 6, lane = tid & 63, m = lane & 15, quad = lane >> 4;
    const int wr = w >> 1, wc = w & 1;
    const int row0 = blockIdx.x * 128, col0 = blockIdx.y * 128;

    const int srow = lane >> 2;
    const int scol = ((lane & 3) ^ ((lane >> 3) & 3)) * 8;
    const unsigned short* gA0 = h   + (size_t)(row0 + w*16      + srow) * E_DIM + scol;
    const unsigned short* gA1 = h   + (size_t)(row0 + w*16 + 64 + srow) * E_DIM + scol;
    const unsigned short* gB0 = Wob + (size_t)(col0 + w*16      + srow) * E_DIM + scol;
    const unsigned short* gB1 = Wob + (size_t)(col0 + w*16 + 64 + srow) * E_DIM + scol;
    const unsigned short* lA0 = As + w * 512;
    const unsigned short* lA1 = As + (w + 4) * 512;
    const unsigned short* lB0 = Bs + w * 512;
    const unsigned short* lB1 = Bs + (w + 4) * 512;

    floatx4 acc[4][4];
#pragma unroll
    for (int i = 0; i < 4; ++i)
#pragma unroll
        for (int j = 0; j < 4; ++j) acc[i][j] = (floatx4){0.f,0.f,0.f,0.f};

    const int aswz = (quad ^ ((m >> 1) & 3)) * 8;

    for (int k0 = 0; k0 < E_DIM; k0 += 32) {
        gload16(gA0 + k0, lA0);
        gload16(gA1 + k0, lA1);
        gload16(gB0 + k0, lB0);
        gload16(gB1 + k0, lB1);
        __syncthreads();
        short8 a[4], b[4];
#pragma unroll
        for (int t = 0; t < 4; ++t) {
            a[t] = *(const short8*)&As[(wr*64 + t*16 + m) * 32 + aswz];
            b[t] = *(const short8*)&Bs[(wc*64 + t*16 + m) * 32 + aswz];
        }
#pragma unroll
        for (int i = 0; i < 4; ++i)
#pragma unroll
            for (int j = 0; j < 4; ++j) acc[i][j] = MFMA16(a[i], b[j], acc[i][j]);
        __syncthreads();
    }

    const int rbase = row0 + wr*64 + quad*4;
    const int cbase = col0 + wc*64 + m;
#pragma unroll
    for (int it = 0; it < 4; ++it)
#pragma unroll
        for (int jt = 0; jt < 4; ++jt)
#pragma unroll
            for (int r = 0; r < 4; ++r) {
                const int row = rbase + it*16 + r;
                const int col = cbase + jt*16;
                out[(size_t)row * D_DIM + col] =
                    acc[it][jt][r] + x[(size_t)row * D_DIM + col] * resS[col];
            }
}

// ---------------------------------------------------------------------------
extern "C" void kernel_launch(void* const* d_in, const int* in_sizes, int n_in,
                              void* d_out, int out_size, void* d_ws, size_t ws_size,
                              hipStream_t stream) {
    const float* x     = (const float*)d_in[0];
    const float* Wuv   = (const float*)d_in[1];
    const float* Wo    = (const float*)d_in[2];
    const float* gamma = (const float*)d_in[3];
    const float* beta  = (const float*)d_in[4];
    const float* g     = (const float*)d_in[5];
    const float* resS  = (const float*)d_in[6];
    float* out = (float*)d_out;

    // ws layout (bf16 elements), ~265 MB total (harness poisons 557.8 MB ws)
    unsigned short* ws   = (unsigned short*)d_ws;
    unsigned short* xn   = ws;                               // NTOK*256
    unsigned short* u    = xn + (size_t)NTOK * D_DIM;        // NTOK*512
    unsigned short* vTg  = u  + (size_t)NTOK * E_DIM;        // CB*512*T_PAD
    unsigned short* qb   = vTg + (size_t)CB * E_DIM * T_PAD; // CH_ROWS*128
    unsigned short* kb   = qb + (size_t)CH_ROWS * S_DIM;     // CH_ROWS*128
    unsigned short* Wuvb = kb + (size_t)CH_ROWS * S_DIM;     // 1152*256
    unsigned short* Wob  = Wuvb + (size_t)N_UV * D_DIM;      // 256*512

    k_castw<<<416, 256, 0, stream>>>(Wuv, Wo, Wuvb, Wob);
    k_rms<<<NTOK / 4, 256, 0, stream>>>(x, g, xn);

    for (int c = 0; c < NCHUNK; ++c) {
        const size_t tok0 = (size_t)c * CH_ROWS;
        k_gemm1<<<dim3(CH_ROWS / 128, 9), 256, 0, stream>>>(
            xn + tok0 * D_DIM, Wuvb, gamma, beta,
            u + tok0 * E_DIM, vTg, qb, kb);
        k_attn<<<dim3(12, CB), 256, 0, stream>>>(qb, kb, vTg, u + tok0 * E_DIM);
    }
    k_gemm2<<<dim3(NTOK / 128, 2), 256, 0, stream>>>(u, Wob, x, resS, out);
}

// Round 3
// 857.098 us; speedup vs baseline: 1.3703x; 1.1179x over previous
//
#include <hip/hip_runtime.h>
#include <cstdint>
#include <cstddef>

#define D_DIM 256
#define E_DIM 512
#define S_DIM 128
#define B_DIM 1024
#define T_SEQ 133
#define N_UV 1152
#define NTOK (B_DIM * T_SEQ)      // 136192 = 1064*128
#define CB 256                    // batches per chunk
#define NCHUNK (B_DIM / CB)       // 4
#define CH_ROWS (CB * T_SEQ)      // 34048 = 266*128
#define EPSF 1e-5f
#define RSQRT_S 0.08838834764831845f

typedef __attribute__((ext_vector_type(8))) short short8;
typedef __attribute__((ext_vector_type(4))) float floatx4;
#define MFMA16(a, b, c) __builtin_amdgcn_mfma_f32_16x16x32_bf16((a), (b), (c), 0, 0, 0)

__device__ __forceinline__ unsigned short f2bf(float f) {
    union { float f; unsigned u; } a; a.f = f;
    unsigned r = a.u + 0x7fffu + ((a.u >> 16) & 1u);
    return (unsigned short)(r >> 16);
}
__device__ __forceinline__ float bf2f(unsigned short h) {
    union { unsigned u; float f; } a; a.u = ((unsigned)h) << 16;
    return a.f;
}

// async global->LDS, 16B per lane; LDS dest = wave-uniform base + lane*16.
__device__ __forceinline__ void gload16(const unsigned short* g, const unsigned short* l) {
    __builtin_amdgcn_global_load_lds(
        (const __attribute__((address_space(1))) unsigned int*)(uintptr_t)g,
        (__attribute__((address_space(3))) unsigned int*)(unsigned)(uintptr_t)l,
        16, 0, 0);
}

// ---------------------------------------------------------------------------
// Cast weights to bf16 once per launch.
// ---------------------------------------------------------------------------
__global__ __launch_bounds__(256) void k_castw(const float* __restrict__ Wuv,
                                               const float* __restrict__ Wo,
                                               unsigned short* __restrict__ Wuvb,
                                               unsigned short* __restrict__ Wob) {
    int i4 = blockIdx.x * 256 + threadIdx.x;
    const int nuv4 = (N_UV * D_DIM) / 4;
    float4 f;
    unsigned short* dst;
    if (i4 < nuv4) { f = ((const float4*)Wuv)[i4]; dst = Wuvb + (size_t)i4 * 4; }
    else { int j = i4 - nuv4; f = ((const float4*)Wo)[j]; dst = Wob + (size_t)j * 4; }
    dst[0] = f2bf(f.x); dst[1] = f2bf(f.y); dst[2] = f2bf(f.z); dst[3] = f2bf(f.w);
}

// ---------------------------------------------------------------------------
// K0: rms-normalize ALL tokens -> bf16 xn. One wave per token. Full batch.
// ---------------------------------------------------------------------------
__global__ __launch_bounds__(256) void k_rms(const float* __restrict__ x,
                                             const float* __restrict__ g,
                                             unsigned short* __restrict__ xn) {
    int wid  = blockIdx.x * 4 + (threadIdx.x >> 6);
    int lane = threadIdx.x & 63;
    float4 vv = ((const float4*)(x + (size_t)wid * D_DIM))[lane];
    float s = vv.x*vv.x + vv.y*vv.y + vv.z*vv.z + vv.w*vv.w;
#pragma unroll
    for (int off = 1; off < 64; off <<= 1) s += __shfl_xor(s, off, 64);
    float sc = g[0] / fmaxf(sqrtf(s) * 0.0625f, EPSF);
    unsigned short o[4] = {f2bf(vv.x*sc), f2bf(vv.y*sc), f2bf(vv.z*sc), f2bf(vv.w*sc)};
    *(ushort4*)(xn + (size_t)wid * D_DIM + lane * 4) = *(const ushort4*)o;
}

// ---------------------------------------------------------------------------
// K1: uv = silu(xn @ Wuv^T). 128x128 tile, BK=32, 2-phase double-buffered
// global_load_lds pipeline, source-permuted LDS swizzle, XCD-local block map.
// Grid (9, 266). Col-blocks 0..3 -> u, 4..7 -> v (row-major), 8 -> q/k.
// ---------------------------------------------------------------------------
__global__ __launch_bounds__(256) void k_gemm1(
    const unsigned short* __restrict__ xn,    // [CH_ROWS][256] chunk-local
    const unsigned short* __restrict__ Wuvb,  // [1152][256]
    const float* __restrict__ gamma, const float* __restrict__ beta,
    unsigned short* __restrict__ u,           // [CH_ROWS][512] chunk-local
    unsigned short* __restrict__ vb,          // [CH_ROWS][512] chunk-local
    unsigned short* __restrict__ q,           // [CH_ROWS][128]
    unsigned short* __restrict__ kk) {        // [CH_ROWS][128]
    __shared__ __align__(16) unsigned short As[2][128 * 32];
    __shared__ __align__(16) unsigned short Bs[2][128 * 32];
    const int tid = threadIdx.x;
    const int w = tid >> 6, lane = tid & 63, m = lane & 15, quad = lane >> 4;
    const int wr = w >> 1, wc = w & 1;

    // XCD-locality: 8 consecutive flat ids = 8 rows (one per XCD); the 9
    // col-blocks of one row-tile land on the same XCD back-to-back.
    const int f = blockIdx.x + 9 * (int)blockIdx.y;   // 0..2393
    int rt, ct;
    if (f < 2376) { rt = (f & 7) | ((f / 72) << 3); ct = (f >> 3) % 9; }
    else { const int gt = f - 2376; rt = 264 + gt / 9; ct = gt - 9 * (gt / 9); }
    const int row0 = rt * 128, col0 = ct * 128;

    // staging: wave w lane l covers LDS row w*16+(l>>2) (+64 for second half),
    // 16B slot (l&3); source col slot permuted: LDS(row,s)=glob(row, s^((rl>>1)&3)).
    const int srow = lane >> 2;
    const int scol = ((lane & 3) ^ ((lane >> 3) & 3)) * 8;
    const unsigned short* gA0 = xn   + (size_t)(row0 + w*16      + srow) * D_DIM + scol;
    const unsigned short* gA1 = xn   + (size_t)(row0 + w*16 + 64 + srow) * D_DIM + scol;
    const unsigned short* gB0 = Wuvb + (size_t)(col0 + w*16      + srow) * D_DIM + scol;
    const unsigned short* gB1 = Wuvb + (size_t)(col0 + w*16 + 64 + srow) * D_DIM + scol;

    floatx4 acc[4][4];
#pragma unroll
    for (int i = 0; i < 4; ++i)
#pragma unroll
        for (int j = 0; j < 4; ++j) acc[i][j] = (floatx4){0.f,0.f,0.f,0.f};

    const int aswz = (quad ^ ((m >> 1) & 3)) * 8;   // read-side inverse swizzle

#define STAGE1(bi, k0) do { \
        gload16(gA0 + (k0), &As[bi][w * 512]);       \
        gload16(gA1 + (k0), &As[bi][(w + 4) * 512]); \
        gload16(gB0 + (k0), &Bs[bi][w * 512]);       \
        gload16(gB1 + (k0), &Bs[bi][(w + 4) * 512]); \
    } while (0)

#define COMP1(bi) do { \
        short8 a_[4], b_[4]; \
        _Pragma("unroll") \
        for (int t = 0; t < 4; ++t) { \
            a_[t] = *(const short8*)&As[bi][(wr*64 + t*16 + m) * 32 + aswz]; \
            b_[t] = *(const short8*)&Bs[bi][(wc*64 + t*16 + m) * 32 + aswz]; \
        } \
        _Pragma("unroll") \
        for (int i = 0; i < 4; ++i) \
            _Pragma("unroll") \
            for (int j = 0; j < 4; ++j) acc[i][j] = MFMA16(a_[i], b_[j], acc[i][j]); \
    } while (0)

    STAGE1(0, 0);
    __syncthreads();                 // tile 0 staged
    int cur = 0;
#pragma unroll 2
    for (int t = 0; t < 7; ++t) {    // 8 k-steps total
        STAGE1(cur ^ 1, (t + 1) * 32);   // issue next tile FIRST
        COMP1(cur);                      // compute hides load latency
        __syncthreads();                 // drain vmcnt (t+1 ready), free cur
        cur ^= 1;
    }
    COMP1(cur);                      // last tile, no prefetch

    const int rbase = row0 + wr*64 + quad*4;
    const int cbase = col0 + wc*64 + m;
#pragma unroll
    for (int it = 0; it < 4; ++it)
#pragma unroll
        for (int jt = 0; jt < 4; ++jt)
#pragma unroll
            for (int r = 0; r < 4; ++r) {
                const int row = rbase + it*16 + r;
                const int col = cbase + jt*16;
                float val = acc[it][jt][r];
                val = val / (1.0f + __expf(-val));   // silu
                if (col0 < E_DIM) {
                    u[(size_t)row * E_DIM + col] = f2bf(val);
                } else if (col0 < 2*E_DIM) {
                    vb[(size_t)row * E_DIM + (col - E_DIM)] = f2bf(val);
                } else {
                    const int s = col - 2*E_DIM;
                    q[(size_t)row * S_DIM + s]  = f2bf(fmaf(val, gamma[s],        beta[s]));
                    kk[(size_t)row * S_DIM + s] = f2bf(fmaf(val, gamma[S_DIM+s], beta[S_DIM+s]));
                }
            }
#undef STAGE1
#undef COMP1
}

// ---------------------------------------------------------------------------
// K2: attention. Grid (12, CB): x = ec(0..3) + 4*ig(0..2), y = local batch.
// V now row-major in global; transpose happens during LDS staging with a
// slot-XOR swizzle (slot = (j>>3) ^ ((e>>3)&7)) to avoid bank conflicts.
// ---------------------------------------------------------------------------
__global__ __launch_bounds__(256) void k_attn(
    const unsigned short* __restrict__ q,
    const unsigned short* __restrict__ kk,
    const unsigned short* __restrict__ v,     // [CH_ROWS][512] chunk-local
    unsigned short* __restrict__ u) {
    __shared__ __align__(16) unsigned short ksh[64][136];  // 17408 B (reused for O)
    __shared__ __align__(16) unsigned short kern[48][72];  //  6912 B
    __shared__ __align__(16) unsigned short VT[128 * 72];  // 18432 B (swizzled vT)
    const int tid = threadIdx.x;
    const int ec = blockIdx.x & 3;
    const int ig = blockIdx.x >> 2;
    const int b  = blockIdx.y;
    const int w = tid >> 6, lane = tid & 63, m = lane & 15, quad = lane >> 4;
    const size_t qs0 = (size_t)b * T_SEQ * S_DIM;
    const size_t vs0 = (size_t)b * T_SEQ * E_DIM;
    const size_t us0 = (size_t)b * T_SEQ * E_DIM;

    short8 qf[3][4];
#pragma unroll
    for (int it = 0; it < 3; ++it) {
        int ri = ig * 48 + it * 16 + m;
        if (ri > T_SEQ - 1) ri = T_SEQ - 1;
        const unsigned short* qp = q + qs0 + (size_t)ri * S_DIM + quad * 8;
#pragma unroll
        for (int ks = 0; ks < 4; ++ks) qf[it][ks] = *(const short8*)(qp + ks * 32);
    }

    floatx4 oa[3][2];
#pragma unroll
    for (int it = 0; it < 3; ++it) {
        oa[it][0] = (floatx4){0.f,0.f,0.f,0.f};
        oa[it][1] = (floatx4){0.f,0.f,0.f,0.f};
    }
    const short8 z8 = {0,0,0,0,0,0,0,0};

    for (int j0 = 0; j0 < T_SEQ; j0 += 64) {
        // stage k-tile [64][128], zero rows >= T
        for (int idx = tid; idx < 1024; idx += 256) {
            int r = idx >> 4, c8 = (idx & 15) * 8;
            short8 val = z8;
            if (j0 + r < T_SEQ)
                val = *(const short8*)(kk + qs0 + (size_t)(j0 + r) * S_DIM + c8);
            *(short8*)&ksh[r][c8] = val;
        }
        // stage v-tile transposed: VT[(e)*72 + swz_slot(j,e)*8 + (j&7)] = v[j][e]
        for (int idx = tid; idx < 1024; idx += 256) {
            int j = idx >> 4, e8 = idx & 15;
            short8 val = z8;
            if (j0 + j < T_SEQ)
                val = *(const short8*)(v + vs0 + (size_t)(j0 + j) * E_DIM + ec * 128 + e8 * 8);
            unsigned short* dst = &VT[(e8 * 8) * 72 + ((((j >> 3) ^ (e8 & 7))) << 3) + (j & 7)];
#pragma unroll
            for (int t = 0; t < 8; ++t) dst[t * 72] = (unsigned short)val[t];
        }
        __syncthreads();

        // phase 1: wave w computes kern cols [w*16, w*16+16) for all 3 i-tiles
        short8 kbf[4];
#pragma unroll
        for (int ks = 0; ks < 4; ++ks)
            kbf[ks] = *(const short8*)&ksh[w*16 + m][ks*32 + quad*8];
        __builtin_amdgcn_s_setprio(1);
#pragma unroll
        for (int it = 0; it < 3; ++it) {
            floatx4 c = (floatx4){0.f,0.f,0.f,0.f};
#pragma unroll
            for (int ks = 0; ks < 4; ++ks) c = MFMA16(qf[it][ks], kbf[ks], c);
#pragma unroll
            for (int r = 0; r < 4; ++r) {
                float sv = fmaxf(c[r] * RSQRT_S, 0.0f);
                kern[it*16 + quad*4 + r][w*16 + m] = f2bf(sv * sv);
            }
        }
        __builtin_amdgcn_s_setprio(0);
        __syncthreads();

        // phase 2: wave w owns e-frags {2w, 2w+1}; O += kern @ v
        __builtin_amdgcn_s_setprio(1);
#pragma unroll
        for (int ef = 0; ef < 2; ++ef) {
            const int eb = w * 2 + ef;
            const int sx = (eb * 2 + (m >> 3)) & 7;
            const unsigned short* vrow = &VT[(eb * 16 + m) * 72];
            short8 b0 = *(const short8*)(vrow + ((quad ^ sx) << 3));
            short8 b1 = *(const short8*)(vrow + (((quad + 4) ^ sx) << 3));
#pragma unroll
            for (int it = 0; it < 3; ++it) {
                short8 a0 = *(const short8*)&kern[it*16 + m][quad*8];
                short8 a1 = *(const short8*)&kern[it*16 + m][32 + quad*8];
                oa[it][ef] = MFMA16(a0, b0, oa[it][ef]);
                oa[it][ef] = MFMA16(a1, b1, oa[it][ef]);
            }
        }
        __builtin_amdgcn_s_setprio(0);
        __syncthreads();
    }

    // stage O into LDS (reuse ksh as [48][136])
#pragma unroll
    for (int it = 0; it < 3; ++it)
#pragma unroll
        for (int ef = 0; ef < 2; ++ef) {
            const int eb = w * 2 + ef;
#pragma unroll
            for (int r = 0; r < 4; ++r)
                ksh[it*16 + quad*4 + r][eb*16 + m] = f2bf(oa[it][ef][r]);
        }
    __syncthreads();

    // h = u * O, coalesced 16B rows
    for (int idx = tid; idx < 48 * 16; idx += 256) {
        const int rl = idx >> 4, c8 = (idx & 15) * 8;
        const int grow = ig * 48 + rl;
        if (grow < T_SEQ) {
            const size_t ad = us0 + (size_t)grow * E_DIM + ec * 128 + c8;
            short8 uv = *(const short8*)(u + ad);
            unsigned short hv[8];
#pragma unroll
            for (int i = 0; i < 8; ++i)
                hv[i] = f2bf(bf2f((unsigned short)uv[i]) * bf2f(ksh[rl][c8 + i]));
            *(short8*)(u + ad) = *(const short8*)hv;
        }
    }
}

// ---------------------------------------------------------------------------
// K3: out = h @ Wo^T + x*res_scale. Full batch, 128x128 tile, K=512,
// 2-phase double-buffered pipeline, XCD-local block map. Grid (2, 1064).
// ---------------------------------------------------------------------------
__global__ __launch_bounds__(256) void k_gemm2(
    const unsigned short* __restrict__ h,     // [NTOK][512]
    const unsigned short* __restrict__ Wob,   // [256][512]
    const float* __restrict__ x, const float* __restrict__ resS,
    float* __restrict__ out) {
    __shared__ __align__(16) unsigned short As[2][128 * 32];
    __shared__ __align__(16) unsigned short Bs[2][128 * 32];
    const int tid = threadIdx.x;
    const int w = tid >> 6, lane = tid & 63, m = lane & 15, quad = lane >> 4;
    const int wr = w >> 1, wc = w & 1;

    const int f = blockIdx.x + 2 * (int)blockIdx.y;   // 0..2127 (= 16*133)
    const int rt = (f & 7) | ((f >> 4) << 3);
    const int ct = (f >> 3) & 1;
    const int row0 = rt * 128, col0 = ct * 128;

    const int srow = lane >> 2;
    const int scol = ((lane & 3) ^ ((lane >> 3) & 3)) * 8;
    const unsigned short* gA0 = h   + (size_t)(row0 + w*16      + srow) * E_DIM + scol;
    const unsigned short* gA1 = h   + (size_t)(row0 + w*16 + 64 + srow) * E_DIM + scol;
    const unsigned short* gB0 = Wob + (size_t)(col0 + w*16      + srow) * E_DIM + scol;
    const unsigned short* gB1 = Wob + (size_t)(col0 + w*16 + 64 + srow) * E_DIM + scol;

    floatx4 acc[4][4];
#pragma unroll
    for (int i = 0; i < 4; ++i)
#pragma unroll
        for (int j = 0; j < 4; ++j) acc[i][j] = (floatx4){0.f,0.f,0.f,0.f};

    const int aswz = (quad ^ ((m >> 1) & 3)) * 8;

#define STAGE2(bi, k0) do { \
        gload16(gA0 + (k0), &As[bi][w * 512]);       \
        gload16(gA1 + (k0), &As[bi][(w + 4) * 512]); \
        gload16(gB0 + (k0), &Bs[bi][w * 512]);       \
        gload16(gB1 + (k0), &Bs[bi][(w + 4) * 512]); \
    } while (0)

#define COMP2(bi) do { \
        short8 a_[4], b_[4]; \
        _Pragma("unroll") \
        for (int t = 0; t < 4; ++t) { \
            a_[t] = *(const short8*)&As[bi][(wr*64 + t*16 + m) * 32 + aswz]; \
            b_[t] = *(const short8*)&Bs[bi][(wc*64 + t*16 + m) * 32 + aswz]; \
        } \
        _Pragma("unroll") \
        for (int i = 0; i < 4; ++i) \
            _Pragma("unroll") \
            for (int j = 0; j < 4; ++j) acc[i][j] = MFMA16(a_[i], b_[j], acc[i][j]); \
    } while (0)

    STAGE2(0, 0);
    __syncthreads();
    int cur = 0;
#pragma unroll 2
    for (int t = 0; t < 15; ++t) {   // 16 k-steps total (K=512)
        STAGE2(cur ^ 1, (t + 1) * 32);
        COMP2(cur);
        __syncthreads();
        cur ^= 1;
    }
    COMP2(cur);

    const int rbase = row0 + wr*64 + quad*4;
    const int cbase = col0 + wc*64 + m;
#pragma unroll
    for (int it = 0; it < 4; ++it)
#pragma unroll
        for (int jt = 0; jt < 4; ++jt)
#pragma unroll
            for (int r = 0; r < 4; ++r) {
                const int row = rbase + it*16 + r;
                const int col = cbase + jt*16;
                out[(size_t)row * D_DIM + col] =
                    acc[it][jt][r] + x[(size_t)row * D_DIM + col] * resS[col];
            }
#undef STAGE2
#undef COMP2
}

// ---------------------------------------------------------------------------
extern "C" void kernel_launch(void* const* d_in, const int* in_sizes, int n_in,
                              void* d_out, int out_size, void* d_ws, size_t ws_size,
                              hipStream_t stream) {
    const float* x     = (const float*)d_in[0];
    const float* Wuv   = (const float*)d_in[1];
    const float* Wo    = (const float*)d_in[2];
    const float* gamma = (const float*)d_in[3];
    const float* beta  = (const float*)d_in[4];
    const float* g     = (const float*)d_in[5];
    const float* resS  = (const float*)d_in[6];
    float* out = (float*)d_out;

    // ws layout (bf16 elements), ~262 MB total
    unsigned short* ws   = (unsigned short*)d_ws;
    unsigned short* xn   = ws;                               // NTOK*256
    unsigned short* u    = xn + (size_t)NTOK * D_DIM;        // NTOK*512
    unsigned short* vb   = u  + (size_t)NTOK * E_DIM;        // CH_ROWS*512
    unsigned short* qb   = vb + (size_t)CH_ROWS * E_DIM;     // CH_ROWS*128
    unsigned short* kb   = qb + (size_t)CH_ROWS * S_DIM;     // CH_ROWS*128
    unsigned short* Wuvb = kb + (size_t)CH_ROWS * S_DIM;     // 1152*256
    unsigned short* Wob  = Wuvb + (size_t)N_UV * D_DIM;      // 256*512

    k_castw<<<416, 256, 0, stream>>>(Wuv, Wo, Wuvb, Wob);
    k_rms<<<NTOK / 4, 256, 0, stream>>>(x, g, xn);

    for (int c = 0; c < NCHUNK; ++c) {
        const size_t tok0 = (size_t)c * CH_ROWS;
        k_gemm1<<<dim3(9, 266), 256, 0, stream>>>(
            xn + tok0 * D_DIM, Wuvb, gamma, beta,
            u + tok0 * E_DIM, vb, qb, kb);
        k_attn<<<dim3(12, CB), 256, 0, stream>>>(qb, kb, vb, u + tok0 * E_DIM);
    }
    k_gemm2<<<dim3(2, NTOK / 128), 256, 0, stream>>>(u, Wob, x, resS, out);
}

// Round 4
// 848.371 us; speedup vs baseline: 1.3844x; 1.0103x over previous
//
#include <hip/hip_runtime.h>
#include <cstdint>
#include <cstddef>

#define D_DIM 256
#define E_DIM 512
#define S_DIM 128
#define B_DIM 1024
#define T_SEQ 133
#define N_UV 1152
#define NTOK (B_DIM * T_SEQ)      // 136192 = 1064*128
#define CB 256                    // batches per chunk
#define NCHUNK (B_DIM / CB)       // 4
#define CH_ROWS (CB * T_SEQ)      // 34048 = 266*128
#define EPSF 1e-5f
#define RSQRT_S 0.08838834764831845f

typedef __attribute__((ext_vector_type(8))) short short8;
typedef __attribute__((ext_vector_type(4))) float floatx4;
#define MFMA16(a, b, c) __builtin_amdgcn_mfma_f32_16x16x32_bf16((a), (b), (c), 0, 0, 0)

// counted vmem wait + raw barrier with compiler memory fences (m139 pattern)
#define VMWAIT(N) asm volatile("s_waitcnt vmcnt(" #N ")" ::: "memory")
#define BAR() do { asm volatile("" ::: "memory"); __builtin_amdgcn_s_barrier(); \
                   asm volatile("" ::: "memory"); } while (0)

__device__ __forceinline__ unsigned short f2bf(float f) {
    union { float f; unsigned u; } a; a.f = f;
    unsigned r = a.u + 0x7fffu + ((a.u >> 16) & 1u);
    return (unsigned short)(r >> 16);
}
__device__ __forceinline__ float bf2f(unsigned short h) {
    union { unsigned u; float f; } a; a.u = ((unsigned)h) << 16;
    return a.f;
}

// async global->LDS, 16B per lane; LDS dest = wave-uniform base + lane*16.
__device__ __forceinline__ void gload16(const unsigned short* g, const unsigned short* l) {
    __builtin_amdgcn_global_load_lds(
        (const __attribute__((address_space(1))) unsigned int*)(uintptr_t)g,
        (__attribute__((address_space(3))) unsigned int*)(unsigned)(uintptr_t)l,
        16, 0, 0);
}

// ---------------------------------------------------------------------------
// Cast weights to bf16 once per launch.
// ---------------------------------------------------------------------------
__global__ __launch_bounds__(256) void k_castw(const float* __restrict__ Wuv,
                                               const float* __restrict__ Wo,
                                               unsigned short* __restrict__ Wuvb,
                                               unsigned short* __restrict__ Wob) {
    int i4 = blockIdx.x * 256 + threadIdx.x;
    const int nuv4 = (N_UV * D_DIM) / 4;
    float4 f;
    unsigned short* dst;
    if (i4 < nuv4) { f = ((const float4*)Wuv)[i4]; dst = Wuvb + (size_t)i4 * 4; }
    else { int j = i4 - nuv4; f = ((const float4*)Wo)[j]; dst = Wob + (size_t)j * 4; }
    dst[0] = f2bf(f.x); dst[1] = f2bf(f.y); dst[2] = f2bf(f.z); dst[3] = f2bf(f.w);
}

// ---------------------------------------------------------------------------
// K0: rms-normalize ALL tokens -> bf16 xn. One wave per token. Full batch.
// ---------------------------------------------------------------------------
__global__ __launch_bounds__(256) void k_rms(const float* __restrict__ x,
                                             const float* __restrict__ g,
                                             unsigned short* __restrict__ xn) {
    int wid  = blockIdx.x * 4 + (threadIdx.x >> 6);
    int lane = threadIdx.x & 63;
    float4 vv = ((const float4*)(x + (size_t)wid * D_DIM))[lane];
    float s = vv.x*vv.x + vv.y*vv.y + vv.z*vv.z + vv.w*vv.w;
#pragma unroll
    for (int off = 1; off < 64; off <<= 1) s += __shfl_xor(s, off, 64);
    float sc = g[0] / fmaxf(sqrtf(s) * 0.0625f, EPSF);
    unsigned short o[4] = {f2bf(vv.x*sc), f2bf(vv.y*sc), f2bf(vv.z*sc), f2bf(vv.w*sc)};
    *(ushort4*)(xn + (size_t)wid * D_DIM + lane * 4) = *(const ushort4*)o;
}

// ---------------------------------------------------------------------------
// K1: uv = silu(xn @ Wuv^T). 128x128 tile, BK=32, depth-3 counted-vmcnt
// pipeline (3 LDS buffers, loads in flight across barriers), source-permuted
// LDS swizzle, XCD-local block map. Grid (9, 266).
// ---------------------------------------------------------------------------
__global__ __launch_bounds__(256) void k_gemm1(
    const unsigned short* __restrict__ xn,    // [CH_ROWS][256] chunk-local
    const unsigned short* __restrict__ Wuvb,  // [1152][256]
    const float* __restrict__ gamma, const float* __restrict__ beta,
    unsigned short* __restrict__ u,           // [CH_ROWS][512] chunk-local
    unsigned short* __restrict__ vb,          // [CH_ROWS][512] chunk-local
    unsigned short* __restrict__ q,           // [CH_ROWS][128]
    unsigned short* __restrict__ kk) {        // [CH_ROWS][128]
    __shared__ __align__(16) unsigned short As[3][128 * 32];
    __shared__ __align__(16) unsigned short Bs[3][128 * 32];
    const int tid = threadIdx.x;
    const int w = tid >> 6, lane = tid & 63, m = lane & 15, quad = lane >> 4;
    const int wr = w >> 1, wc = w & 1;

    // XCD-locality: 8 consecutive flat ids = 8 rows (one per XCD); the 9
    // col-blocks of one row-tile land on the same XCD back-to-back.
    const int f = blockIdx.x + 9 * (int)blockIdx.y;   // 0..2393
    int rt, ct;
    if (f < 2376) { rt = (f & 7) | ((f / 72) << 3); ct = (f >> 3) % 9; }
    else { const int gt = f - 2376; rt = 264 + gt / 9; ct = gt - 9 * (gt / 9); }
    const int row0 = rt * 128, col0 = ct * 128;

    const int srow = lane >> 2;
    const int scol = ((lane & 3) ^ ((lane >> 3) & 3)) * 8;
    const unsigned short* gA0 = xn   + (size_t)(row0 + w*16      + srow) * D_DIM + scol;
    const unsigned short* gA1 = xn   + (size_t)(row0 + w*16 + 64 + srow) * D_DIM + scol;
    const unsigned short* gB0 = Wuvb + (size_t)(col0 + w*16      + srow) * D_DIM + scol;
    const unsigned short* gB1 = Wuvb + (size_t)(col0 + w*16 + 64 + srow) * D_DIM + scol;

    floatx4 acc[4][4];
#pragma unroll
    for (int i = 0; i < 4; ++i)
#pragma unroll
        for (int j = 0; j < 4; ++j) acc[i][j] = (floatx4){0.f,0.f,0.f,0.f};

    const int aswz = (quad ^ ((m >> 1) & 3)) * 8;   // read-side inverse swizzle

#define STAGE1(bi, k0) do { \
        gload16(gA0 + (k0), &As[bi][w * 512]);       \
        gload16(gA1 + (k0), &As[bi][(w + 4) * 512]); \
        gload16(gB0 + (k0), &Bs[bi][w * 512]);       \
        gload16(gB1 + (k0), &Bs[bi][(w + 4) * 512]); \
    } while (0)

#define COMP1(bi) do { \
        short8 a_[4], b_[4]; \
        _Pragma("unroll") \
        for (int t_ = 0; t_ < 4; ++t_) { \
            a_[t_] = *(const short8*)&As[bi][(wr*64 + t_*16 + m) * 32 + aswz]; \
            b_[t_] = *(const short8*)&Bs[bi][(wc*64 + t_*16 + m) * 32 + aswz]; \
        } \
        _Pragma("unroll") \
        for (int i_ = 0; i_ < 4; ++i_) \
            _Pragma("unroll") \
            for (int j_ = 0; j_ < 4; ++j_) acc[i_][j_] = MFMA16(a_[i_], b_[j_], acc[i_][j_]); \
    } while (0)

    // depth-3 pipeline over 8 k-steps (BK=32, D=256)
    STAGE1(0, 0);
    STAGE1(1, 32);                    // 8 loads/wave in flight
    {
        int s0 = 0, s1 = 1, s2 = 2;
#pragma unroll
        for (int t = 0; t < 6; ++t) {
            STAGE1(s2, (t + 2) * 32); // 12 in flight
            VMWAIT(8);                // step-t tile resident
            BAR();
            COMP1(s0);
            BAR();                    // buf s0 free for reuse
            int tmp = s0; s0 = s1; s1 = s2; s2 = tmp;
        }
        VMWAIT(4); BAR(); COMP1(s0); BAR();
        VMWAIT(0); BAR(); COMP1(s1);
    }

    const int rbase = row0 + wr*64 + quad*4;
    const int cbase = col0 + wc*64 + m;
#pragma unroll
    for (int it = 0; it < 4; ++it)
#pragma unroll
        for (int jt = 0; jt < 4; ++jt)
#pragma unroll
            for (int r = 0; r < 4; ++r) {
                const int row = rbase + it*16 + r;
                const int col = cbase + jt*16;
                float val = acc[it][jt][r];
                val = val / (1.0f + __expf(-val));   // silu
                if (col0 < E_DIM) {
                    u[(size_t)row * E_DIM + col] = f2bf(val);
                } else if (col0 < 2*E_DIM) {
                    vb[(size_t)row * E_DIM + (col - E_DIM)] = f2bf(val);
                } else {
                    const int s = col - 2*E_DIM;
                    q[(size_t)row * S_DIM + s]  = f2bf(fmaf(val, gamma[s],        beta[s]));
                    kk[(size_t)row * S_DIM + s] = f2bf(fmaf(val, gamma[S_DIM+s], beta[S_DIM+s]));
                }
            }
#undef STAGE1
#undef COMP1
}

// ---------------------------------------------------------------------------
// K2: attention. Grid (12, CB): x = ec(0..3) + 4*ig(0..2), y = local batch.
// V row-major in global; transpose during LDS staging with slot-XOR swizzle.
// ---------------------------------------------------------------------------
__global__ __launch_bounds__(256) void k_attn(
    const unsigned short* __restrict__ q,
    const unsigned short* __restrict__ kk,
    const unsigned short* __restrict__ v,     // [CH_ROWS][512] chunk-local
    unsigned short* __restrict__ u) {
    __shared__ __align__(16) unsigned short ksh[64][136];  // 17408 B (reused for O)
    __shared__ __align__(16) unsigned short kern[48][72];  //  6912 B
    __shared__ __align__(16) unsigned short VT[128 * 72];  // 18432 B (swizzled vT)
    const int tid = threadIdx.x;
    const int ec = blockIdx.x & 3;
    const int ig = blockIdx.x >> 2;
    const int b  = blockIdx.y;
    const int w = tid >> 6, lane = tid & 63, m = lane & 15, quad = lane >> 4;
    const size_t qs0 = (size_t)b * T_SEQ * S_DIM;
    const size_t vs0 = (size_t)b * T_SEQ * E_DIM;
    const size_t us0 = (size_t)b * T_SEQ * E_DIM;

    short8 qf[3][4];
#pragma unroll
    for (int it = 0; it < 3; ++it) {
        int ri = ig * 48 + it * 16 + m;
        if (ri > T_SEQ - 1) ri = T_SEQ - 1;
        const unsigned short* qp = q + qs0 + (size_t)ri * S_DIM + quad * 8;
#pragma unroll
        for (int ks = 0; ks < 4; ++ks) qf[it][ks] = *(const short8*)(qp + ks * 32);
    }

    floatx4 oa[3][2];
#pragma unroll
    for (int it = 0; it < 3; ++it) {
        oa[it][0] = (floatx4){0.f,0.f,0.f,0.f};
        oa[it][1] = (floatx4){0.f,0.f,0.f,0.f};
    }
    const short8 z8 = {0,0,0,0,0,0,0,0};

    for (int j0 = 0; j0 < T_SEQ; j0 += 64) {
        // stage k-tile [64][128], zero rows >= T
        for (int idx = tid; idx < 1024; idx += 256) {
            int r = idx >> 4, c8 = (idx & 15) * 8;
            short8 val = z8;
            if (j0 + r < T_SEQ)
                val = *(const short8*)(kk + qs0 + (size_t)(j0 + r) * S_DIM + c8);
            *(short8*)&ksh[r][c8] = val;
        }
        // stage v-tile transposed: VT[e*72 + swz_slot(j,e)*8 + (j&7)] = v[j][e]
        for (int idx = tid; idx < 1024; idx += 256) {
            int j = idx >> 4, e8 = idx & 15;
            short8 val = z8;
            if (j0 + j < T_SEQ)
                val = *(const short8*)(v + vs0 + (size_t)(j0 + j) * E_DIM + ec * 128 + e8 * 8);
            unsigned short* dst = &VT[(e8 * 8) * 72 + ((((j >> 3) ^ (e8 & 7))) << 3) + (j & 7)];
#pragma unroll
            for (int t = 0; t < 8; ++t) dst[t * 72] = (unsigned short)val[t];
        }
        __syncthreads();

        // phase 1: wave w computes kern cols [w*16, w*16+16) for all 3 i-tiles
        short8 kbf[4];
#pragma unroll
        for (int ks = 0; ks < 4; ++ks)
            kbf[ks] = *(const short8*)&ksh[w*16 + m][ks*32 + quad*8];
        __builtin_amdgcn_s_setprio(1);
#pragma unroll
        for (int it = 0; it < 3; ++it) {
            floatx4 c = (floatx4){0.f,0.f,0.f,0.f};
#pragma unroll
            for (int ks = 0; ks < 4; ++ks) c = MFMA16(qf[it][ks], kbf[ks], c);
#pragma unroll
            for (int r = 0; r < 4; ++r) {
                float sv = fmaxf(c[r] * RSQRT_S, 0.0f);
                kern[it*16 + quad*4 + r][w*16 + m] = f2bf(sv * sv);
            }
        }
        __builtin_amdgcn_s_setprio(0);
        __syncthreads();

        // phase 2: wave w owns e-frags {2w, 2w+1}; O += kern @ v
        __builtin_amdgcn_s_setprio(1);
#pragma unroll
        for (int ef = 0; ef < 2; ++ef) {
            const int eb = w * 2 + ef;
            const int sx = (eb * 2 + (m >> 3)) & 7;
            const unsigned short* vrow = &VT[(eb * 16 + m) * 72];
            short8 b0 = *(const short8*)(vrow + ((quad ^ sx) << 3));
            short8 b1 = *(const short8*)(vrow + (((quad + 4) ^ sx) << 3));
#pragma unroll
            for (int it = 0; it < 3; ++it) {
                short8 a0 = *(const short8*)&kern[it*16 + m][quad*8];
                short8 a1 = *(const short8*)&kern[it*16 + m][32 + quad*8];
                oa[it][ef] = MFMA16(a0, b0, oa[it][ef]);
                oa[it][ef] = MFMA16(a1, b1, oa[it][ef]);
            }
        }
        __builtin_amdgcn_s_setprio(0);
        __syncthreads();
    }

    // stage O into LDS (reuse ksh as [48][136])
#pragma unroll
    for (int it = 0; it < 3; ++it)
#pragma unroll
        for (int ef = 0; ef < 2; ++ef) {
            const int eb = w * 2 + ef;
#pragma unroll
            for (int r = 0; r < 4; ++r)
                ksh[it*16 + quad*4 + r][eb*16 + m] = f2bf(oa[it][ef][r]);
        }
    __syncthreads();

    // h = u * O, coalesced 16B rows
    for (int idx = tid; idx < 48 * 16; idx += 256) {
        const int rl = idx >> 4, c8 = (idx & 15) * 8;
        const int grow = ig * 48 + rl;
        if (grow < T_SEQ) {
            const size_t ad = us0 + (size_t)grow * E_DIM + ec * 128 + c8;
            short8 uv = *(const short8*)(u + ad);
            unsigned short hv[8];
#pragma unroll
            for (int i = 0; i < 8; ++i)
                hv[i] = f2bf(bf2f((unsigned short)uv[i]) * bf2f(ksh[rl][c8 + i]));
            *(short8*)(u + ad) = *(const short8*)hv;
        }
    }
}

// ---------------------------------------------------------------------------
// K3: out = h @ Wo^T + x*res_scale. Full batch, 128x128 tile, K=512,
// depth-3 counted-vmcnt pipeline, XCD-local block map. Grid (2, 1064).
// ---------------------------------------------------------------------------
__global__ __launch_bounds__(256) void k_gemm2(
    const unsigned short* __restrict__ h,     // [NTOK][512]
    const unsigned short* __restrict__ Wob,   // [256][512]
    const float* __restrict__ x, const float* __restrict__ resS,
    float* __restrict__ out) {
    __shared__ __align__(16) unsigned short As[3][128 * 32];
    __shared__ __align__(16) unsigned short Bs[3][128 * 32];
    const int tid = threadIdx.x;
    const int w = tid >> 6, lane = tid & 63, m = lane & 15, quad = lane >> 4;
    const int wr = w >> 1, wc = w & 1;

    const int f = blockIdx.x + 2 * (int)blockIdx.y;   // 0..2127 (= 16*133)
    const int rt = (f & 7) | ((f >> 4) << 3);
    const int ct = (f >> 3) & 1;
    const int row0 = rt * 128, col0 = ct * 128;

    const int srow = lane >> 2;
    const int scol = ((lane & 3) ^ ((lane >> 3) & 3)) * 8;
    const unsigned short* gA0 = h   + (size_t)(row0 + w*16      + srow) * E_DIM + scol;
    const unsigned short* gA1 = h   + (size_t)(row0 + w*16 + 64 + srow) * E_DIM + scol;
    const unsigned short* gB0 = Wob + (size_t)(col0 + w*16      + srow) * E_DIM + scol;
    const unsigned short* gB1 = Wob + (size_t)(col0 + w*16 + 64 + srow) * E_DIM + scol;

    floatx4 acc[4][4];
#pragma unroll
    for (int i = 0; i < 4; ++i)
#pragma unroll
        for (int j = 0; j < 4; ++j) acc[i][j] = (floatx4){0.f,0.f,0.f,0.f};

    const int aswz = (quad ^ ((m >> 1) & 3)) * 8;

#define STAGE2(bi, k0) do { \
        gload16(gA0 + (k0), &As[bi][w * 512]);       \
        gload16(gA1 + (k0), &As[bi][(w + 4) * 512]); \
        gload16(gB0 + (k0), &Bs[bi][w * 512]);       \
        gload16(gB1 + (k0), &Bs[bi][(w + 4) * 512]); \
    } while (0)

#define COMP2(bi) do { \
        short8 a_[4], b_[4]; \
        _Pragma("unroll") \
        for (int t_ = 0; t_ < 4; ++t_) { \
            a_[t_] = *(const short8*)&As[bi][(wr*64 + t_*16 + m) * 32 + aswz]; \
            b_[t_] = *(const short8*)&Bs[bi][(wc*64 + t_*16 + m) * 32 + aswz]; \
        } \
        _Pragma("unroll") \
        for (int i_ = 0; i_ < 4; ++i_) \
            _Pragma("unroll") \
            for (int j_ = 0; j_ < 4; ++j_) acc[i_][j_] = MFMA16(a_[i_], b_[j_], acc[i_][j_]); \
    } while (0)

    // depth-3 pipeline over 16 k-steps (BK=32, K=512)
    STAGE2(0, 0);
    STAGE2(1, 32);
    {
        int s0 = 0, s1 = 1, s2 = 2;
#pragma unroll
        for (int t = 0; t < 14; ++t) {
            STAGE2(s2, (t + 2) * 32);
            VMWAIT(8);
            BAR();
            COMP2(s0);
            BAR();
            int tmp = s0; s0 = s1; s1 = s2; s2 = tmp;
        }
        VMWAIT(4); BAR(); COMP2(s0); BAR();
        VMWAIT(0); BAR(); COMP2(s1);
    }

    const int rbase = row0 + wr*64 + quad*4;
    const int cbase = col0 + wc*64 + m;
#pragma unroll
    for (int it = 0; it < 4; ++it)
#pragma unroll
        for (int jt = 0; jt < 4; ++jt)
#pragma unroll
            for (int r = 0; r < 4; ++r) {
                const int row = rbase + it*16 + r;
                const int col = cbase + jt*16;
                out[(size_t)row * D_DIM + col] =
                    acc[it][jt][r] + x[(size_t)row * D_DIM + col] * resS[col];
            }
#undef STAGE2
#undef COMP2
}

// ---------------------------------------------------------------------------
extern "C" void kernel_launch(void* const* d_in, const int* in_sizes, int n_in,
                              void* d_out, int out_size, void* d_ws, size_t ws_size,
                              hipStream_t stream) {
    const float* x     = (const float*)d_in[0];
    const float* Wuv   = (const float*)d_in[1];
    const float* Wo    = (const float*)d_in[2];
    const float* gamma = (const float*)d_in[3];
    const float* beta  = (const float*)d_in[4];
    const float* g     = (const float*)d_in[5];
    const float* resS  = (const float*)d_in[6];
    float* out = (float*)d_out;

    // ws layout (bf16 elements), ~262 MB total
    unsigned short* ws   = (unsigned short*)d_ws;
    unsigned short* xn   = ws;                               // NTOK*256
    unsigned short* u    = xn + (size_t)NTOK * D_DIM;        // NTOK*512
    unsigned short* vb   = u  + (size_t)NTOK * E_DIM;        // CH_ROWS*512
    unsigned short* qb   = vb + (size_t)CH_ROWS * E_DIM;     // CH_ROWS*128
    unsigned short* kb   = qb + (size_t)CH_ROWS * S_DIM;     // CH_ROWS*128
    unsigned short* Wuvb = kb + (size_t)CH_ROWS * S_DIM;     // 1152*256
    unsigned short* Wob  = Wuvb + (size_t)N_UV * D_DIM;      // 256*512

    k_castw<<<416, 256, 0, stream>>>(Wuv, Wo, Wuvb, Wob);
    k_rms<<<NTOK / 4, 256, 0, stream>>>(x, g, xn);

    for (int c = 0; c < NCHUNK; ++c) {
        const size_t tok0 = (size_t)c * CH_ROWS;
        k_gemm1<<<dim3(9, 266), 256, 0, stream>>>(
            xn + tok0 * D_DIM, Wuvb, gamma, beta,
            u + tok0 * E_DIM, vb, qb, kb);
        k_attn<<<dim3(12, CB), 256, 0, stream>>>(qb, kb, vb, u + tok0 * E_DIM);
    }
    k_gemm2<<<dim3(2, NTOK / 128), 256, 0, stream>>>(u, Wob, x, resS, out);
}

// Round 5
// 837.387 us; speedup vs baseline: 1.4025x; 1.0131x over previous
//
#include <hip/hip_runtime.h>
#include <cstdint>
#include <cstddef>

#define D_DIM 256
#define E_DIM 512
#define S_DIM 128
#define B_DIM 1024
#define T_SEQ 133
#define N_UV 1152
#define NTOK (B_DIM * T_SEQ)      // 136192 = 1064*128
#define CB 256                    // batches per chunk
#define NCHUNK (B_DIM / CB)       // 4
#define CH_ROWS (CB * T_SEQ)      // 34048 = 266*128
#define EPSF 1e-5f
#define RSQRT_S 0.08838834764831845f

typedef __attribute__((ext_vector_type(8))) short short8;
typedef __attribute__((ext_vector_type(4))) float floatx4;
#define MFMA16(a, b, c) __builtin_amdgcn_mfma_f32_16x16x32_bf16((a), (b), (c), 0, 0, 0)

// counted vmem wait + raw barrier with compiler memory fences (m139 pattern)
#define VMWAIT(N) asm volatile("s_waitcnt vmcnt(" #N ")" ::: "memory")
#define BAR() do { asm volatile("" ::: "memory"); __builtin_amdgcn_s_barrier(); \
                   asm volatile("" ::: "memory"); } while (0)

__device__ __forceinline__ unsigned short f2bf(float f) {
    union { float f; unsigned u; } a; a.f = f;
    unsigned r = a.u + 0x7fffu + ((a.u >> 16) & 1u);
    return (unsigned short)(r >> 16);
}
__device__ __forceinline__ float bf2f(unsigned short h) {
    union { unsigned u; float f; } a; a.u = ((unsigned)h) << 16;
    return a.f;
}

// async global->LDS, 16B per lane; LDS dest = wave-uniform base + lane*16.
__device__ __forceinline__ void gload16(const unsigned short* g, const unsigned short* l) {
    __builtin_amdgcn_global_load_lds(
        (const __attribute__((address_space(1))) unsigned int*)(uintptr_t)g,
        (__attribute__((address_space(3))) unsigned int*)(unsigned)(uintptr_t)l,
        16, 0, 0);
}

// ---------------------------------------------------------------------------
// Cast weights to bf16 once per launch.
// ---------------------------------------------------------------------------
__global__ __launch_bounds__(256) void k_castw(const float* __restrict__ Wuv,
                                               const float* __restrict__ Wo,
                                               unsigned short* __restrict__ Wuvb,
                                               unsigned short* __restrict__ Wob) {
    int i4 = blockIdx.x * 256 + threadIdx.x;
    const int nuv4 = (N_UV * D_DIM) / 4;
    float4 f;
    unsigned short* dst;
    if (i4 < nuv4) { f = ((const float4*)Wuv)[i4]; dst = Wuvb + (size_t)i4 * 4; }
    else { int j = i4 - nuv4; f = ((const float4*)Wo)[j]; dst = Wob + (size_t)j * 4; }
    dst[0] = f2bf(f.x); dst[1] = f2bf(f.y); dst[2] = f2bf(f.z); dst[3] = f2bf(f.w);
}

// ---------------------------------------------------------------------------
// K0: rms-normalize ALL tokens -> bf16 xn. One wave per token. Full batch.
// ---------------------------------------------------------------------------
__global__ __launch_bounds__(256) void k_rms(const float* __restrict__ x,
                                             const float* __restrict__ g,
                                             unsigned short* __restrict__ xn) {
    int wid  = blockIdx.x * 4 + (threadIdx.x >> 6);
    int lane = threadIdx.x & 63;
    float4 vv = ((const float4*)(x + (size_t)wid * D_DIM))[lane];
    float s = vv.x*vv.x + vv.y*vv.y + vv.z*vv.z + vv.w*vv.w;
#pragma unroll
    for (int off = 1; off < 64; off <<= 1) s += __shfl_xor(s, off, 64);
    float sc = g[0] / fmaxf(sqrtf(s) * 0.0625f, EPSF);
    unsigned short o[4] = {f2bf(vv.x*sc), f2bf(vv.y*sc), f2bf(vv.z*sc), f2bf(vv.w*sc)};
    *(ushort4*)(xn + (size_t)wid * D_DIM + lane * 4) = *(const ushort4*)o;
}

// ---------------------------------------------------------------------------
// K1: uv = silu(xn @ Wuv^T). 128x128 tile, BK=64 (full 128B-line staging:
// each gload16 covers 8 rows x 128B contiguous), double-buffered counted-vmcnt
// pipeline, slot-XOR LDS swizzle via source permutation. Grid (9, 266).
// ---------------------------------------------------------------------------
__global__ __launch_bounds__(256) void k_gemm1(
    const unsigned short* __restrict__ xn,    // [CH_ROWS][256] chunk-local
    const unsigned short* __restrict__ Wuvb,  // [1152][256]
    const float* __restrict__ gamma, const float* __restrict__ beta,
    unsigned short* __restrict__ u,           // [CH_ROWS][512] chunk-local
    unsigned short* __restrict__ vb,          // [CH_ROWS][512] chunk-local
    unsigned short* __restrict__ q,           // [CH_ROWS][128]
    unsigned short* __restrict__ kk) {        // [CH_ROWS][128]
    __shared__ __align__(16) unsigned short As[2][128 * 64];  // 32 KB
    __shared__ __align__(16) unsigned short Bs[2][128 * 64];  // 32 KB
    const int tid = threadIdx.x;
    const int w = tid >> 6, lane = tid & 63, m = lane & 15, quad = lane >> 4;
    const int wr = w >> 1, wc = w & 1;

    // XCD-locality: row-tile's 9 col-blocks land on the same XCD.
    const int f = blockIdx.x + 9 * (int)blockIdx.y;   // 0..2393
    int rt, ct;
    if (f < 2376) { rt = (f & 7) | ((f / 72) << 3); ct = (f >> 3) % 9; }
    else { const int gt = f - 2376; rt = 264 + gt / 9; ct = gt - 9 * (gt / 9); }
    const int row0 = rt * 128, col0 = ct * 128;

    // staging: inst i of wave w covers rows w*32+i*8 .. +7, full 64-el rows.
    // lane l: row offset l>>3, col slot (l&7)^(l>>3) (inverse swizzle at src).
    const int sr8 = lane >> 3;
    const int sc8 = ((lane & 7) ^ sr8) * 8;
    const unsigned short* gA = xn   + (size_t)(row0 + w*32 + sr8) * D_DIM + sc8;
    const unsigned short* gB = Wuvb + (size_t)(col0 + w*32 + sr8) * D_DIM + sc8;

    floatx4 acc[4][4];
#pragma unroll
    for (int i = 0; i < 4; ++i)
#pragma unroll
        for (int j = 0; j < 4; ++j) acc[i][j] = (floatx4){0.f,0.f,0.f,0.f};

    const int mq = m & 7;

#define STAGE1(bi, k0) do { \
        gload16(gA + (k0),             &As[bi][(w*4+0)*512]); \
        gload16(gA + (k0) +  8*D_DIM,  &As[bi][(w*4+1)*512]); \
        gload16(gA + (k0) + 16*D_DIM,  &As[bi][(w*4+2)*512]); \
        gload16(gA + (k0) + 24*D_DIM,  &As[bi][(w*4+3)*512]); \
        gload16(gB + (k0),             &Bs[bi][(w*4+0)*512]); \
        gload16(gB + (k0) +  8*D_DIM,  &Bs[bi][(w*4+1)*512]); \
        gload16(gB + (k0) + 16*D_DIM,  &Bs[bi][(w*4+2)*512]); \
        gload16(gB + (k0) + 24*D_DIM,  &Bs[bi][(w*4+3)*512]); \
    } while (0)

#define COMP1(bi) do { \
        _Pragma("unroll") \
        for (int kx = 0; kx < 2; ++kx) { \
            const int sw = ((kx*4 + quad) ^ mq) * 8; \
            short8 a_[4], b_[4]; \
            _Pragma("unroll") \
            for (int t_ = 0; t_ < 4; ++t_) { \
                a_[t_] = *(const short8*)&As[bi][(wr*64 + t_*16 + m) * 64 + sw]; \
                b_[t_] = *(const short8*)&Bs[bi][(wc*64 + t_*16 + m) * 64 + sw]; \
            } \
            _Pragma("unroll") \
            for (int i_ = 0; i_ < 4; ++i_) \
                _Pragma("unroll") \
                for (int j_ = 0; j_ < 4; ++j_) \
                    acc[i_][j_] = MFMA16(a_[i_], b_[j_], acc[i_][j_]); \
        } \
    } while (0)

    // 4 k-steps (BK=64, D=256), depth-2, counted vmcnt
    STAGE1(0, 0);
    STAGE1(1, 64);
    VMWAIT(8); BAR(); COMP1(0); BAR(); STAGE1(0, 128);
    VMWAIT(8); BAR(); COMP1(1); BAR(); STAGE1(1, 192);
    VMWAIT(8); BAR(); COMP1(0); BAR();
    VMWAIT(0); BAR(); COMP1(1);

    const int rbase = row0 + wr*64 + quad*4;
    const int cbase = col0 + wc*64 + m;
#pragma unroll
    for (int it = 0; it < 4; ++it)
#pragma unroll
        for (int jt = 0; jt < 4; ++jt)
#pragma unroll
            for (int r = 0; r < 4; ++r) {
                const int row = rbase + it*16 + r;
                const int col = cbase + jt*16;
                float val = acc[it][jt][r];
                val = val / (1.0f + __expf(-val));   // silu
                if (col0 < E_DIM) {
                    u[(size_t)row * E_DIM + col] = f2bf(val);
                } else if (col0 < 2*E_DIM) {
                    vb[(size_t)row * E_DIM + (col - E_DIM)] = f2bf(val);
                } else {
                    const int s = col - 2*E_DIM;
                    q[(size_t)row * S_DIM + s]  = f2bf(fmaf(val, gamma[s],        beta[s]));
                    kk[(size_t)row * S_DIM + s] = f2bf(fmaf(val, gamma[S_DIM+s], beta[S_DIM+s]));
                }
            }
#undef STAGE1
#undef COMP1
}

// ---------------------------------------------------------------------------
// K2: attention. Grid (12, CB): x = ec(0..3) + 4*ig(0..2), y = local batch.
// V row-major in global; transpose during LDS staging with slot-XOR swizzle.
// ---------------------------------------------------------------------------
__global__ __launch_bounds__(256) void k_attn(
    const unsigned short* __restrict__ q,
    const unsigned short* __restrict__ kk,
    const unsigned short* __restrict__ v,     // [CH_ROWS][512] chunk-local
    unsigned short* __restrict__ u) {
    __shared__ __align__(16) unsigned short ksh[64][136];  // 17408 B (reused for O)
    __shared__ __align__(16) unsigned short kern[48][72];  //  6912 B
    __shared__ __align__(16) unsigned short VT[128 * 72];  // 18432 B (swizzled vT)
    const int tid = threadIdx.x;
    const int ec = blockIdx.x & 3;
    const int ig = blockIdx.x >> 2;
    const int b  = blockIdx.y;
    const int w = tid >> 6, lane = tid & 63, m = lane & 15, quad = lane >> 4;
    const size_t qs0 = (size_t)b * T_SEQ * S_DIM;
    const size_t vs0 = (size_t)b * T_SEQ * E_DIM;
    const size_t us0 = (size_t)b * T_SEQ * E_DIM;

    short8 qf[3][4];
#pragma unroll
    for (int it = 0; it < 3; ++it) {
        int ri = ig * 48 + it * 16 + m;
        if (ri > T_SEQ - 1) ri = T_SEQ - 1;
        const unsigned short* qp = q + qs0 + (size_t)ri * S_DIM + quad * 8;
#pragma unroll
        for (int ks = 0; ks < 4; ++ks) qf[it][ks] = *(const short8*)(qp + ks * 32);
    }

    floatx4 oa[3][2];
#pragma unroll
    for (int it = 0; it < 3; ++it) {
        oa[it][0] = (floatx4){0.f,0.f,0.f,0.f};
        oa[it][1] = (floatx4){0.f,0.f,0.f,0.f};
    }
    const short8 z8 = {0,0,0,0,0,0,0,0};

    for (int j0 = 0; j0 < T_SEQ; j0 += 64) {
        // stage k-tile [64][128], zero rows >= T
        for (int idx = tid; idx < 1024; idx += 256) {
            int r = idx >> 4, c8 = (idx & 15) * 8;
            short8 val = z8;
            if (j0 + r < T_SEQ)
                val = *(const short8*)(kk + qs0 + (size_t)(j0 + r) * S_DIM + c8);
            *(short8*)&ksh[r][c8] = val;
        }
        // stage v-tile transposed: VT[e*72 + swz_slot(j,e)*8 + (j&7)] = v[j][e]
        for (int idx = tid; idx < 1024; idx += 256) {
            int j = idx >> 4, e8 = idx & 15;
            short8 val = z8;
            if (j0 + j < T_SEQ)
                val = *(const short8*)(v + vs0 + (size_t)(j0 + j) * E_DIM + ec * 128 + e8 * 8);
            unsigned short* dst = &VT[(e8 * 8) * 72 + ((((j >> 3) ^ (e8 & 7))) << 3) + (j & 7)];
#pragma unroll
            for (int t = 0; t < 8; ++t) dst[t * 72] = (unsigned short)val[t];
        }
        __syncthreads();

        // phase 1: wave w computes kern cols [w*16, w*16+16) for all 3 i-tiles
        short8 kbf[4];
#pragma unroll
        for (int ks = 0; ks < 4; ++ks)
            kbf[ks] = *(const short8*)&ksh[w*16 + m][ks*32 + quad*8];
        __builtin_amdgcn_s_setprio(1);
#pragma unroll
        for (int it = 0; it < 3; ++it) {
            floatx4 c = (floatx4){0.f,0.f,0.f,0.f};
#pragma unroll
            for (int ks = 0; ks < 4; ++ks) c = MFMA16(qf[it][ks], kbf[ks], c);
#pragma unroll
            for (int r = 0; r < 4; ++r) {
                float sv = fmaxf(c[r] * RSQRT_S, 0.0f);
                kern[it*16 + quad*4 + r][w*16 + m] = f2bf(sv * sv);
            }
        }
        __builtin_amdgcn_s_setprio(0);
        __syncthreads();

        // phase 2: wave w owns e-frags {2w, 2w+1}; O += kern @ v
        __builtin_amdgcn_s_setprio(1);
#pragma unroll
        for (int ef = 0; ef < 2; ++ef) {
            const int eb = w * 2 + ef;
            const int sx = (eb * 2 + (m >> 3)) & 7;
            const unsigned short* vrow = &VT[(eb * 16 + m) * 72];
            short8 b0 = *(const short8*)(vrow + ((quad ^ sx) << 3));
            short8 b1 = *(const short8*)(vrow + (((quad + 4) ^ sx) << 3));
#pragma unroll
            for (int it = 0; it < 3; ++it) {
                short8 a0 = *(const short8*)&kern[it*16 + m][quad*8];
                short8 a1 = *(const short8*)&kern[it*16 + m][32 + quad*8];
                oa[it][ef] = MFMA16(a0, b0, oa[it][ef]);
                oa[it][ef] = MFMA16(a1, b1, oa[it][ef]);
            }
        }
        __builtin_amdgcn_s_setprio(0);
        __syncthreads();
    }

    // stage O into LDS (reuse ksh as [48][136])
#pragma unroll
    for (int it = 0; it < 3; ++it)
#pragma unroll
        for (int ef = 0; ef < 2; ++ef) {
            const int eb = w * 2 + ef;
#pragma unroll
            for (int r = 0; r < 4; ++r)
                ksh[it*16 + quad*4 + r][eb*16 + m] = f2bf(oa[it][ef][r]);
        }
    __syncthreads();

    // h = u * O, coalesced 16B rows
    for (int idx = tid; idx < 48 * 16; idx += 256) {
        const int rl = idx >> 4, c8 = (idx & 15) * 8;
        const int grow = ig * 48 + rl;
        if (grow < T_SEQ) {
            const size_t ad = us0 + (size_t)grow * E_DIM + ec * 128 + c8;
            short8 uv = *(const short8*)(u + ad);
            unsigned short hv[8];
#pragma unroll
            for (int i = 0; i < 8; ++i)
                hv[i] = f2bf(bf2f((unsigned short)uv[i]) * bf2f(ksh[rl][c8 + i]));
            *(short8*)(u + ad) = *(const short8*)hv;
        }
    }
}

// ---------------------------------------------------------------------------
// K3: out = h @ Wo^T + x*res_scale. Full batch, 128x128 tile, BK=64,
// double-buffered counted-vmcnt pipeline, XCD-local map. Grid (2, 1064).
// ---------------------------------------------------------------------------
__global__ __launch_bounds__(256) void k_gemm2(
    const unsigned short* __restrict__ h,     // [NTOK][512]
    const unsigned short* __restrict__ Wob,   // [256][512]
    const float* __restrict__ x, const float* __restrict__ resS,
    float* __restrict__ out) {
    __shared__ __align__(16) unsigned short As[2][128 * 64];  // 32 KB
    __shared__ __align__(16) unsigned short Bs[2][128 * 64];  // 32 KB
    const int tid = threadIdx.x;
    const int w = tid >> 6, lane = tid & 63, m = lane & 15, quad = lane >> 4;
    const int wr = w >> 1, wc = w & 1;

    const int f = blockIdx.x + 2 * (int)blockIdx.y;   // 0..2127
    const int rt = (f & 7) | ((f >> 4) << 3);
    const int ct = (f >> 3) & 1;
    const int row0 = rt * 128, col0 = ct * 128;

    const int sr8 = lane >> 3;
    const int sc8 = ((lane & 7) ^ sr8) * 8;
    const unsigned short* gA = h   + (size_t)(row0 + w*32 + sr8) * E_DIM + sc8;
    const unsigned short* gB = Wob + (size_t)(col0 + w*32 + sr8) * E_DIM + sc8;

    floatx4 acc[4][4];
#pragma unroll
    for (int i = 0; i < 4; ++i)
#pragma unroll
        for (int j = 0; j < 4; ++j) acc[i][j] = (floatx4){0.f,0.f,0.f,0.f};

    const int mq = m & 7;

#define STAGE2(bi, k0) do { \
        gload16(gA + (k0),             &As[bi][(w*4+0)*512]); \
        gload16(gA + (k0) +  8*E_DIM,  &As[bi][(w*4+1)*512]); \
        gload16(gA + (k0) + 16*E_DIM,  &As[bi][(w*4+2)*512]); \
        gload16(gA + (k0) + 24*E_DIM,  &As[bi][(w*4+3)*512]); \
        gload16(gB + (k0),             &Bs[bi][(w*4+0)*512]); \
        gload16(gB + (k0) +  8*E_DIM,  &Bs[bi][(w*4+1)*512]); \
        gload16(gB + (k0) + 16*E_DIM,  &Bs[bi][(w*4+2)*512]); \
        gload16(gB + (k0) + 24*E_DIM,  &Bs[bi][(w*4+3)*512]); \
    } while (0)

#define COMP2(bi) do { \
        _Pragma("unroll") \
        for (int kx = 0; kx < 2; ++kx) { \
            const int sw = ((kx*4 + quad) ^ mq) * 8; \
            short8 a_[4], b_[4]; \
            _Pragma("unroll") \
            for (int t_ = 0; t_ < 4; ++t_) { \
                a_[t_] = *(const short8*)&As[bi][(wr*64 + t_*16 + m) * 64 + sw]; \
                b_[t_] = *(const short8*)&Bs[bi][(wc*64 + t_*16 + m) * 64 + sw]; \
            } \
            _Pragma("unroll") \
            for (int i_ = 0; i_ < 4; ++i_) \
                _Pragma("unroll") \
                for (int j_ = 0; j_ < 4; ++j_) \
                    acc[i_][j_] = MFMA16(a_[i_], b_[j_], acc[i_][j_]); \
        } \
    } while (0)

    // 8 k-steps (BK=64, K=512), depth-2, counted vmcnt
    STAGE2(0, 0);
    STAGE2(1, 64);
#pragma unroll
    for (int t = 0; t < 8; ++t) {
        if (t < 7) { VMWAIT(8); } else { VMWAIT(0); }
        BAR();
        COMP2(t & 1);
        if (t < 6) { BAR(); STAGE2(t & 1, (t + 2) * 64); }
    }

    const int rbase = row0 + wr*64 + quad*4;
    const int cbase = col0 + wc*64 + m;
#pragma unroll
    for (int it = 0; it < 4; ++it)
#pragma unroll
        for (int jt = 0; jt < 4; ++jt)
#pragma unroll
            for (int r = 0; r < 4; ++r) {
                const int row = rbase + it*16 + r;
                const int col = cbase + jt*16;
                out[(size_t)row * D_DIM + col] =
                    acc[it][jt][r] + x[(size_t)row * D_DIM + col] * resS[col];
            }
#undef STAGE2
#undef COMP2
}

// ---------------------------------------------------------------------------
extern "C" void kernel_launch(void* const* d_in, const int* in_sizes, int n_in,
                              void* d_out, int out_size, void* d_ws, size_t ws_size,
                              hipStream_t stream) {
    const float* x     = (const float*)d_in[0];
    const float* Wuv   = (const float*)d_in[1];
    const float* Wo    = (const float*)d_in[2];
    const float* gamma = (const float*)d_in[3];
    const float* beta  = (const float*)d_in[4];
    const float* g     = (const float*)d_in[5];
    const float* resS  = (const float*)d_in[6];
    float* out = (float*)d_out;

    // ws layout (bf16 elements), ~262 MB total
    unsigned short* ws   = (unsigned short*)d_ws;
    unsigned short* xn   = ws;                               // NTOK*256
    unsigned short* u    = xn + (size_t)NTOK * D_DIM;        // NTOK*512
    unsigned short* vb   = u  + (size_t)NTOK * E_DIM;        // CH_ROWS*512
    unsigned short* qb   = vb + (size_t)CH_ROWS * E_DIM;     // CH_ROWS*128
    unsigned short* kb   = qb + (size_t)CH_ROWS * S_DIM;     // CH_ROWS*128
    unsigned short* Wuvb = kb + (size_t)CH_ROWS * S_DIM;     // 1152*256
    unsigned short* Wob  = Wuvb + (size_t)N_UV * D_DIM;      // 256*512

    k_castw<<<416, 256, 0, stream>>>(Wuv, Wo, Wuvb, Wob);
    k_rms<<<NTOK / 4, 256, 0, stream>>>(x, g, xn);

    for (int c = 0; c < NCHUNK; ++c) {
        const size_t tok0 = (size_t)c * CH_ROWS;
        k_gemm1<<<dim3(9, 266), 256, 0, stream>>>(
            xn + tok0 * D_DIM, Wuvb, gamma, beta,
            u + tok0 * E_DIM, vb, qb, kb);
        k_attn<<<dim3(12, CB), 256, 0, stream>>>(qb, kb, vb, u + tok0 * E_DIM);
    }
    k_gemm2<<<dim3(2, NTOK / 128), 256, 0, stream>>>(u, Wob, x, resS, out);
}

// Round 7
// 778.167 us; speedup vs baseline: 1.5092x; 1.0761x over previous
//
#include <hip/hip_runtime.h>
#include <cstdint>
#include <cstddef>

#define D_DIM 256
#define E_DIM 512
#define S_DIM 128
#define B_DIM 1024
#define T_SEQ 133
#define N_UV 1152
#define NTOK (B_DIM * T_SEQ)      // 136192 = 1064*128
#define CB 256                    // batches per chunk
#define NCHUNK (B_DIM / CB)       // 4
#define CH_ROWS (CB * T_SEQ)      // 34048 = 266*128
#define EPSF 1e-5f
#define RSQRT_S 0.08838834764831845f

typedef __attribute__((ext_vector_type(8))) short short8;
typedef __attribute__((ext_vector_type(4))) float floatx4;
#define MFMA16(a, b, c) __builtin_amdgcn_mfma_f32_16x16x32_bf16((a), (b), (c), 0, 0, 0)

// counted vmem wait + raw barrier with compiler memory fences (m139 pattern)
#define VMWAIT(N) asm volatile("s_waitcnt vmcnt(" #N ")" ::: "memory")
#define LGKM0()   asm volatile("s_waitcnt lgkmcnt(0)" ::: "memory")
#define BAR() do { asm volatile("" ::: "memory"); __builtin_amdgcn_s_barrier(); \
                   asm volatile("" ::: "memory"); } while (0)

__device__ __forceinline__ unsigned short f2bf(float f) {
    union { float f; unsigned u; } a; a.f = f;
    unsigned r = a.u + 0x7fffu + ((a.u >> 16) & 1u);
    return (unsigned short)(r >> 16);
}
__device__ __forceinline__ float bf2f(unsigned short h) {
    union { unsigned u; float f; } a; a.u = ((unsigned)h) << 16;
    return a.f;
}

// async global->LDS, 16B per lane; LDS dest = wave-uniform base + lane*16.
__device__ __forceinline__ void gload16(const unsigned short* g, const unsigned short* l) {
    __builtin_amdgcn_global_load_lds(
        (const __attribute__((address_space(1))) unsigned int*)(uintptr_t)g,
        (__attribute__((address_space(3))) unsigned int*)(unsigned)(uintptr_t)l,
        16, 0, 0);
}

// ---------------------------------------------------------------------------
// Cast weights to bf16 once per launch.
// ---------------------------------------------------------------------------
__global__ __launch_bounds__(256) void k_castw(const float* __restrict__ Wuv,
                                               const float* __restrict__ Wo,
                                               unsigned short* __restrict__ Wuvb,
                                               unsigned short* __restrict__ Wob) {
    int i4 = blockIdx.x * 256 + threadIdx.x;
    const int nuv4 = (N_UV * D_DIM) / 4;
    float4 f;
    unsigned short* dst;
    if (i4 < nuv4) { f = ((const float4*)Wuv)[i4]; dst = Wuvb + (size_t)i4 * 4; }
    else { int j = i4 - nuv4; f = ((const float4*)Wo)[j]; dst = Wob + (size_t)j * 4; }
    dst[0] = f2bf(f.x); dst[1] = f2bf(f.y); dst[2] = f2bf(f.z); dst[3] = f2bf(f.w);
}

// ---------------------------------------------------------------------------
// K0: rms-normalize ALL tokens -> bf16 xn. One wave per token. Full batch.
// ---------------------------------------------------------------------------
__global__ __launch_bounds__(256) void k_rms(const float* __restrict__ x,
                                             const float* __restrict__ g,
                                             unsigned short* __restrict__ xn) {
    int wid  = blockIdx.x * 4 + (threadIdx.x >> 6);
    int lane = threadIdx.x & 63;
    float4 vv = ((const float4*)(x + (size_t)wid * D_DIM))[lane];
    float s = vv.x*vv.x + vv.y*vv.y + vv.z*vv.z + vv.w*vv.w;
#pragma unroll
    for (int off = 1; off < 64; off <<= 1) s += __shfl_xor(s, off, 64);
    float sc = g[0] / fmaxf(sqrtf(s) * 0.0625f, EPSF);
    unsigned short o[4] = {f2bf(vv.x*sc), f2bf(vv.y*sc), f2bf(vv.z*sc), f2bf(vv.w*sc)};
    *(ushort4*)(xn + (size_t)wid * D_DIM + lane * 4) = *(const ushort4*)o;
}

// ---------------------------------------------------------------------------
// K1: uv = silu(xn @ Wuv^T). 128x128 tile, BK=64 (full 128B-line staging),
// double-buffered counted-vmcnt pipeline, slot-XOR LDS swizzle via source
// permutation, LDS-staged coalesced epilogue. Grid (9, 266).
// ---------------------------------------------------------------------------
__global__ __launch_bounds__(256) void k_gemm1(
    const unsigned short* __restrict__ xn,    // [CH_ROWS][256] chunk-local
    const unsigned short* __restrict__ Wuvb,  // [1152][256]
    const float* __restrict__ gamma, const float* __restrict__ beta,
    unsigned short* __restrict__ u,           // [CH_ROWS][512] chunk-local
    unsigned short* __restrict__ vb,          // [CH_ROWS][512] chunk-local
    unsigned short* __restrict__ q,           // [CH_ROWS][128]
    unsigned short* __restrict__ kk) {        // [CH_ROWS][128]
    __shared__ __align__(16) unsigned short SH[4][8192];   // 64 KB total
#define AS1(bi) (&SH[(bi)][0])
#define BS1(bi) (&SH[2 + (bi)][0])
    const int tid = threadIdx.x;
    const int w = tid >> 6, lane = tid & 63, m = lane & 15, quad = lane >> 4;
    const int wr = w >> 1, wc = w & 1;

    // XCD-locality: row-tile's 9 col-blocks land on the same XCD.
    const int f = blockIdx.x + 9 * (int)blockIdx.y;   // 0..2393
    int rt, ct;
    if (f < 2376) { rt = (f & 7) | ((f / 72) << 3); ct = (f >> 3) % 9; }
    else { const int gt = f - 2376; rt = 264 + gt / 9; ct = gt - 9 * (gt / 9); }
    const int row0 = rt * 128, col0 = ct * 128;

    // staging: inst i of wave w covers rows w*32+i*8 .. +7, full 64-el rows.
    const int sr8 = lane >> 3;
    const int sc8 = ((lane & 7) ^ sr8) * 8;
    const unsigned short* gA = xn   + (size_t)(row0 + w*32 + sr8) * D_DIM + sc8;
    const unsigned short* gB = Wuvb + (size_t)(col0 + w*32 + sr8) * D_DIM + sc8;

    floatx4 acc[4][4];
#pragma unroll
    for (int i = 0; i < 4; ++i)
#pragma unroll
        for (int j = 0; j < 4; ++j) acc[i][j] = (floatx4){0.f,0.f,0.f,0.f};

    const int mq = m & 7;

#define STAGE1(bi, k0) do { \
        gload16(gA + (k0),             AS1(bi) + 0*512 + w*2048); \
        gload16(gA + (k0) +  8*D_DIM,  AS1(bi) + 1*512 + w*2048); \
        gload16(gA + (k0) + 16*D_DIM,  AS1(bi) + 2*512 + w*2048); \
        gload16(gA + (k0) + 24*D_DIM,  AS1(bi) + 3*512 + w*2048); \
        gload16(gB + (k0),             BS1(bi) + 0*512 + w*2048); \
        gload16(gB + (k0) +  8*D_DIM,  BS1(bi) + 1*512 + w*2048); \
        gload16(gB + (k0) + 16*D_DIM,  BS1(bi) + 2*512 + w*2048); \
        gload16(gB + (k0) + 24*D_DIM,  BS1(bi) + 3*512 + w*2048); \
    } while (0)

#define COMP1(bi) do { \
        _Pragma("unroll") \
        for (int kx = 0; kx < 2; ++kx) { \
            const int sw = ((kx*4 + quad) ^ mq) * 8; \
            short8 a_[4], b_[4]; \
            _Pragma("unroll") \
            for (int t_ = 0; t_ < 4; ++t_) { \
                a_[t_] = *(const short8*)(AS1(bi) + (wr*64 + t_*16 + m) * 64 + sw); \
                b_[t_] = *(const short8*)(BS1(bi) + (wc*64 + t_*16 + m) * 64 + sw); \
            } \
            _Pragma("unroll") \
            for (int i_ = 0; i_ < 4; ++i_) \
                _Pragma("unroll") \
                for (int j_ = 0; j_ < 4; ++j_) \
                    acc[i_][j_] = MFMA16(a_[i_], b_[j_], acc[i_][j_]); \
        } \
    } while (0)

    // 4 k-steps (BK=64, D=256), depth-2, counted vmcnt
    STAGE1(0, 0);
    STAGE1(1, 64);
    VMWAIT(8); BAR(); COMP1(0); BAR(); STAGE1(0, 128);
    VMWAIT(8); BAR(); COMP1(1); BAR(); STAGE1(1, 192);
    VMWAIT(8); BAR(); COMP1(0); BAR();
    VMWAIT(0); BAR(); COMP1(1);

    // silu in place
#pragma unroll
    for (int it = 0; it < 4; ++it)
#pragma unroll
        for (int jt = 0; jt < 4; ++jt)
#pragma unroll
            for (int r = 0; r < 4; ++r) {
                float val = acc[it][jt][r];
                acc[it][jt][r] = val / (1.0f + __expf(-val));
            }

    // LDS-staged coalesced epilogue (tile 128x128 bf16, stride 136).
    // LGKM0 before the barrier: all COMP ds_reads complete in every wave
    // before any wave begins overwriting SH (raw s_barrier doesn't drain).
    LGKM0(); BAR();
    unsigned short* S0 = &SH[0][0];
    const int rl0 = wr*64 + quad*4;
    const int cl0 = wc*64 + m;
    if (col0 < 2*E_DIM) {
#pragma unroll
        for (int it = 0; it < 4; ++it)
#pragma unroll
            for (int jt = 0; jt < 4; ++jt)
#pragma unroll
                for (int r = 0; r < 4; ++r)
                    S0[(rl0 + it*16 + r) * 136 + cl0 + jt*16] = f2bf(acc[it][jt][r]);
        LGKM0(); BAR();
        unsigned short* dst = (col0 < E_DIM) ? u : vb;
        const int cg = (col0 < E_DIM) ? col0 : col0 - E_DIM;
        for (int idx = tid; idx < 2048; idx += 256) {
            const int rl = idx >> 4, c8 = (idx & 15) * 8;
            *(short8*)(dst + (size_t)(row0 + rl) * E_DIM + cg + c8) =
                *(const short8*)&S0[rl * 136 + c8];
        }
    } else {
        // q then k, two staged passes; s-index == local col
#pragma unroll
        for (int pp = 0; pp < 2; ++pp) {
            const float* gm = gamma + pp * S_DIM;
            const float* bt = beta  + pp * S_DIM;
#pragma unroll
            for (int jt = 0; jt < 4; ++jt) {
                const int s = cl0 + jt*16;
                const float gv = gm[s], bv = bt[s];
#pragma unroll
                for (int it = 0; it < 4; ++it)
#pragma unroll
                    for (int r = 0; r < 4; ++r)
                        S0[(rl0 + it*16 + r) * 136 + s] =
                            f2bf(fmaf(acc[it][jt][r], gv, bv));
            }
            LGKM0(); BAR();
            unsigned short* dst = pp ? kk : q;
            for (int idx = tid; idx < 2048; idx += 256) {
                const int rl = idx >> 4, c8 = (idx & 15) * 8;
                *(short8*)(dst + (size_t)(row0 + rl) * S_DIM + c8) =
                    *(const short8*)&S0[rl * 136 + c8];
            }
            if (pp == 0) { LGKM0(); BAR(); }
        }
    }
#undef STAGE1
#undef COMP1
#undef AS1
#undef BS1
}

// ---------------------------------------------------------------------------
// K2: attention. Grid (12, CB): x = ec(0..3) + 4*ig(0..2), y = local batch.
// V row-major in global; transpose during LDS staging with slot-XOR swizzle.
// ---------------------------------------------------------------------------
__global__ __launch_bounds__(256) void k_attn(
    const unsigned short* __restrict__ q,
    const unsigned short* __restrict__ kk,
    const unsigned short* __restrict__ v,     // [CH_ROWS][512] chunk-local
    unsigned short* __restrict__ u) {
    __shared__ __align__(16) unsigned short ksh[64][136];  // 17408 B (reused for O)
    __shared__ __align__(16) unsigned short kern[48][72];  //  6912 B
    __shared__ __align__(16) unsigned short VT[128 * 72];  // 18432 B (swizzled vT)
    const int tid = threadIdx.x;
    const int ec = blockIdx.x & 3;
    const int ig = blockIdx.x >> 2;
    const int b  = blockIdx.y;
    const int w = tid >> 6, lane = tid & 63, m = lane & 15, quad = lane >> 4;
    const size_t qs0 = (size_t)b * T_SEQ * S_DIM;
    const size_t vs0 = (size_t)b * T_SEQ * E_DIM;
    const size_t us0 = (size_t)b * T_SEQ * E_DIM;

    short8 qf[3][4];
#pragma unroll
    for (int it = 0; it < 3; ++it) {
        int ri = ig * 48 + it * 16 + m;
        if (ri > T_SEQ - 1) ri = T_SEQ - 1;
        const unsigned short* qp = q + qs0 + (size_t)ri * S_DIM + quad * 8;
#pragma unroll
        for (int ks = 0; ks < 4; ++ks) qf[it][ks] = *(const short8*)(qp + ks * 32);
    }

    floatx4 oa[3][2];
#pragma unroll
    for (int it = 0; it < 3; ++it) {
        oa[it][0] = (floatx4){0.f,0.f,0.f,0.f};
        oa[it][1] = (floatx4){0.f,0.f,0.f,0.f};
    }
    const short8 z8 = {0,0,0,0,0,0,0,0};

    for (int j0 = 0; j0 < T_SEQ; j0 += 64) {
        // stage k-tile [64][128], zero rows >= T
        for (int idx = tid; idx < 1024; idx += 256) {
            int r = idx >> 4, c8 = (idx & 15) * 8;
            short8 val = z8;
            if (j0 + r < T_SEQ)
                val = *(const short8*)(kk + qs0 + (size_t)(j0 + r) * S_DIM + c8);
            *(short8*)&ksh[r][c8] = val;
        }
        // stage v-tile transposed: VT[e*72 + swz_slot(j,e)*8 + (j&7)] = v[j][e]
        for (int idx = tid; idx < 1024; idx += 256) {
            int j = idx >> 4, e8 = idx & 15;
            short8 val = z8;
            if (j0 + j < T_SEQ)
                val = *(const short8*)(v + vs0 + (size_t)(j0 + j) * E_DIM + ec * 128 + e8 * 8);
            unsigned short* dst = &VT[(e8 * 8) * 72 + ((((j >> 3) ^ (e8 & 7))) << 3) + (j & 7)];
#pragma unroll
            for (int t = 0; t < 8; ++t) dst[t * 72] = (unsigned short)val[t];
        }
        __syncthreads();

        // phase 1: wave w computes kern cols [w*16, w*16+16) for all 3 i-tiles
        short8 kbf[4];
#pragma unroll
        for (int ks = 0; ks < 4; ++ks)
            kbf[ks] = *(const short8*)&ksh[w*16 + m][ks*32 + quad*8];
        __builtin_amdgcn_s_setprio(1);
#pragma unroll
        for (int it = 0; it < 3; ++it) {
            floatx4 c = (floatx4){0.f,0.f,0.f,0.f};
#pragma unroll
            for (int ks = 0; ks < 4; ++ks) c = MFMA16(qf[it][ks], kbf[ks], c);
#pragma unroll
            for (int r = 0; r < 4; ++r) {
                float sv = fmaxf(c[r] * RSQRT_S, 0.0f);
                kern[it*16 + quad*4 + r][w*16 + m] = f2bf(sv * sv);
            }
        }
        __builtin_amdgcn_s_setprio(0);
        __syncthreads();

        // phase 2: wave w owns e-frags {2w, 2w+1}; O += kern @ v
        __builtin_amdgcn_s_setprio(1);
#pragma unroll
        for (int ef = 0; ef < 2; ++ef) {
            const int eb = w * 2 + ef;
            const int sx = (eb * 2 + (m >> 3)) & 7;
            const unsigned short* vrow = &VT[(eb * 16 + m) * 72];
            short8 b0 = *(const short8*)(vrow + ((quad ^ sx) << 3));
            short8 b1 = *(const short8*)(vrow + (((quad + 4) ^ sx) << 3));
#pragma unroll
            for (int it = 0; it < 3; ++it) {
                short8 a0 = *(const short8*)&kern[it*16 + m][quad*8];
                short8 a1 = *(const short8*)&kern[it*16 + m][32 + quad*8];
                oa[it][ef] = MFMA16(a0, b0, oa[it][ef]);
                oa[it][ef] = MFMA16(a1, b1, oa[it][ef]);
            }
        }
        __builtin_amdgcn_s_setprio(0);
        __syncthreads();
    }

    // stage O into LDS (reuse ksh as [48][136])
#pragma unroll
    for (int it = 0; it < 3; ++it)
#pragma unroll
        for (int ef = 0; ef < 2; ++ef) {
            const int eb = w * 2 + ef;
#pragma unroll
            for (int r = 0; r < 4; ++r)
                ksh[it*16 + quad*4 + r][eb*16 + m] = f2bf(oa[it][ef][r]);
        }
    __syncthreads();

    // h = u * O, coalesced 16B rows
    for (int idx = tid; idx < 48 * 16; idx += 256) {
        const int rl = idx >> 4, c8 = (idx & 15) * 8;
        const int grow = ig * 48 + rl;
        if (grow < T_SEQ) {
            const size_t ad = us0 + (size_t)grow * E_DIM + ec * 128 + c8;
            short8 uv = *(const short8*)(u + ad);
            unsigned short hv[8];
#pragma unroll
            for (int i = 0; i < 8; ++i)
                hv[i] = f2bf(bf2f((unsigned short)uv[i]) * bf2f(ksh[rl][c8 + i]));
            *(short8*)(u + ad) = *(const short8*)hv;
        }
    }
}

// ---------------------------------------------------------------------------
// K3: out = h @ Wo^T + x*res_scale. Full batch, 128x128 tile, BK=64,
// double-buffered counted-vmcnt pipeline, LDS-staged f32 epilogue.
// Grid (2, 1064).
// ---------------------------------------------------------------------------
__global__ __launch_bounds__(256) void k_gemm2(
    const unsigned short* __restrict__ h,     // [NTOK][512]
    const unsigned short* __restrict__ Wob,   // [256][512]
    const float* __restrict__ x, const float* __restrict__ resS,
    float* __restrict__ out) {
    __shared__ __align__(16) unsigned short SH[4][8192];   // 64 KB total
#define AS2(bi) (&SH[(bi)][0])
#define BS2(bi) (&SH[2 + (bi)][0])
    const int tid = threadIdx.x;
    const int w = tid >> 6, lane = tid & 63, m = lane & 15, quad = lane >> 4;
    const int wr = w >> 1, wc = w & 1;

    const int f = blockIdx.x + 2 * (int)blockIdx.y;   // 0..2127
    const int rt = (f & 7) | ((f >> 4) << 3);
    const int ct = (f >> 3) & 1;
    const int row0 = rt * 128, col0 = ct * 128;

    const int sr8 = lane >> 3;
    const int sc8 = ((lane & 7) ^ sr8) * 8;
    const unsigned short* gA = h   + (size_t)(row0 + w*32 + sr8) * E_DIM + sc8;
    const unsigned short* gB = Wob + (size_t)(col0 + w*32 + sr8) * E_DIM + sc8;

    floatx4 acc[4][4];
#pragma unroll
    for (int i = 0; i < 4; ++i)
#pragma unroll
        for (int j = 0; j < 4; ++j) acc[i][j] = (floatx4){0.f,0.f,0.f,0.f};

    const int mq = m & 7;

#define STAGE2(bi, k0) do { \
        gload16(gA + (k0),             AS2(bi) + 0*512 + w*2048); \
        gload16(gA + (k0) +  8*E_DIM,  AS2(bi) + 1*512 + w*2048); \
        gload16(gA + (k0) + 16*E_DIM,  AS2(bi) + 2*512 + w*2048); \
        gload16(gA + (k0) + 24*E_DIM,  AS2(bi) + 3*512 + w*2048); \
        gload16(gB + (k0),             BS2(bi) + 0*512 + w*2048); \
        gload16(gB + (k0) +  8*E_DIM,  BS2(bi) + 1*512 + w*2048); \
        gload16(gB + (k0) + 16*E_DIM,  BS2(bi) + 2*512 + w*2048); \
        gload16(gB + (k0) + 24*E_DIM,  BS2(bi) + 3*512 + w*2048); \
    } while (0)

#define COMP2(bi) do { \
        _Pragma("unroll") \
        for (int kx = 0; kx < 2; ++kx) { \
            const int sw = ((kx*4 + quad) ^ mq) * 8; \
            short8 a_[4], b_[4]; \
            _Pragma("unroll") \
            for (int t_ = 0; t_ < 4; ++t_) { \
                a_[t_] = *(const short8*)(AS2(bi) + (wr*64 + t_*16 + m) * 64 + sw); \
                b_[t_] = *(const short8*)(BS2(bi) + (wc*64 + t_*16 + m) * 64 + sw); \
            } \
            _Pragma("unroll") \
            for (int i_ = 0; i_ < 4; ++i_) \
                _Pragma("unroll") \
                for (int j_ = 0; j_ < 4; ++j_) \
                    acc[i_][j_] = MFMA16(a_[i_], b_[j_], acc[i_][j_]); \
        } \
    } while (0)

    // 8 k-steps (BK=64, K=512), depth-2, counted vmcnt
    STAGE2(0, 0);
    STAGE2(1, 64);
#pragma unroll
    for (int t = 0; t < 8; ++t) {
        if (t < 7) { VMWAIT(8); } else { VMWAIT(0); }
        BAR();
        COMP2(t & 1);
        if (t < 6) { BAR(); STAGE2(t & 1, (t + 2) * 64); }
    }

    // LDS-staged f32 epilogue: two 64-row passes, stride 132 (pad 4).
    LGKM0(); BAR();
    float* F = (float*)&SH[0][0];
    const int rl0 = quad * 4;                 // local row within wave's 64-row half
    const int cl0 = wc*64 + m;
#pragma unroll
    for (int pp = 0; pp < 2; ++pp) {
        if (wr == pp) {
#pragma unroll
            for (int it = 0; it < 4; ++it)
#pragma unroll
                for (int jt = 0; jt < 4; ++jt)
#pragma unroll
                    for (int r = 0; r < 4; ++r)
                        F[(it*16 + rl0 + r) * 132 + cl0 + jt*16] = acc[it][jt][r];
        }
        LGKM0(); BAR();
        for (int idx = tid; idx < 2048; idx += 256) {
            const int rl = idx >> 5, c4 = (idx & 31) * 4;
            const int grow = row0 + pp*64 + rl, gcol = col0 + c4;
            const float4 xv = *(const float4*)(x + (size_t)grow * D_DIM + gcol);
            const float4 rv = *(const float4*)(resS + gcol);
            float4 ov;
            ov.x = F[rl*132 + c4 + 0] + xv.x * rv.x;
            ov.y = F[rl*132 + c4 + 1] + xv.y * rv.y;
            ov.z = F[rl*132 + c4 + 2] + xv.z * rv.z;
            ov.w = F[rl*132 + c4 + 3] + xv.w * rv.w;
            *(float4*)(out + (size_t)grow * D_DIM + gcol) = ov;
        }
        if (pp == 0) { LGKM0(); BAR(); }
    }
#undef STAGE2
#undef COMP2
#undef AS2
#undef BS2
}

// ---------------------------------------------------------------------------
extern "C" void kernel_launch(void* const* d_in, const int* in_sizes, int n_in,
                              void* d_out, int out_size, void* d_ws, size_t ws_size,
                              hipStream_t stream) {
    const float* x     = (const float*)d_in[0];
    const float* Wuv   = (const float*)d_in[1];
    const float* Wo    = (const float*)d_in[2];
    const float* gamma = (const float*)d_in[3];
    const float* beta  = (const float*)d_in[4];
    const float* g     = (const float*)d_in[5];
    const float* resS  = (const float*)d_in[6];
    float* out = (float*)d_out;

    // ws layout (bf16 elements), ~262 MB total
    unsigned short* ws   = (unsigned short*)d_ws;
    unsigned short* xn   = ws;                               // NTOK*256
    unsigned short* u    = xn + (size_t)NTOK * D_DIM;        // NTOK*512
    unsigned short* vb   = u  + (size_t)NTOK * E_DIM;        // CH_ROWS*512
    unsigned short* qb   = vb + (size_t)CH_ROWS * E_DIM;     // CH_ROWS*128
    unsigned short* kb   = qb + (size_t)CH_ROWS * S_DIM;     // CH_ROWS*128
    unsigned short* Wuvb = kb + (size_t)CH_ROWS * S_DIM;     // 1152*256
    unsigned short* Wob  = Wuvb + (size_t)N_UV * D_DIM;      // 256*512

    k_castw<<<416, 256, 0, stream>>>(Wuv, Wo, Wuvb, Wob);
    k_rms<<<NTOK / 4, 256, 0, stream>>>(x, g, xn);

    for (int c = 0; c < NCHUNK; ++c) {
        const size_t tok0 = (size_t)c * CH_ROWS;
        k_gemm1<<<dim3(9, 266), 256, 0, stream>>>(
            xn + tok0 * D_DIM, Wuvb, gamma, beta,
            u + tok0 * E_DIM, vb, qb, kb);
        k_attn<<<dim3(12, CB), 256, 0, stream>>>(qb, kb, vb, u + tok0 * E_DIM);
    }
    k_gemm2<<<dim3(2, NTOK / 128), 256, 0, stream>>>(u, Wob, x, resS, out);
}